// Round 1
// 363.115 us; speedup vs baseline: 1.3376x; 1.3376x over previous
//
#include <hip/hip_runtime.h>
#include <math.h>

#define BN_EPS 1e-5f
#define NSLOT1 15376  // conv1: one slot per block (14400 interior + 976 border)
#define NSLOT2 12544  // conv2 3136*4

typedef __attribute__((ext_vector_type(8))) _Float16 f16x8;
typedef __attribute__((ext_vector_type(4))) float f32x4;

// ---------- helpers ----------

__device__ __forceinline__ float siluf(float v) {
    return v / (1.0f + __expf(-v));
}

// Cubic B-spline basis (4 funcs) on uniform knots g[j] = 2*j - 7.
__device__ __forceinline__ void bspline4(float x, float b[4]) {
    float u = (x + 7.0f) * 0.5f;
    float jf = floorf(u);
    float t = u - jf;
    float t2 = t * t, t3 = t2 * t;
    float omt = 1.0f - t;
    float v0 = t3 * (1.0f / 6.0f);
    float v1 = (-3.0f * t3 + 3.0f * t2 + 3.0f * t + 1.0f) * (1.0f / 6.0f);
    float v2 = (3.0f * t3 - 6.0f * t2 + 4.0f) * (1.0f / 6.0f);
    float v3 = omt * omt * omt * (1.0f / 6.0f);
    int j = (int)jf;
#pragma unroll
    for (int i = 0; i < 4; ++i) {
        int d = j - i;
        b[i] = (d == 0) ? v0 : (d == 1) ? v1 : (d == 2) ? v2 : (d == 3) ? v3 : 0.0f;
    }
}

// ---------- pre-convert conv1 weights to f16 ----------
// K layout: k = g*16 + ql*5 + f for value i = g*3+ql (i = c*4+dy*2+dx), f=0..4
// (f==0 -> silu weight, f=1..4 -> spline). k = g*16+15 is zero pad.

__global__ __launch_bounds__(256) void wconv1h_kernel(
        const float* __restrict__ bw, const float* __restrict__ sw,
        _Float16* __restrict__ Wf1) {
    int t = blockIdx.x * 256 + threadIdx.x;
    if (t >= 32 * 64) return;
    int n = t >> 6;
    int k = t & 63;
    int g = k >> 4, loc = k & 15;
    float val = 0.f;
    if (loc < 15) {
        int ql = loc / 5, f = loc - ql * 5;
        int i = g * 3 + ql;
        val = (f == 0) ? bw[n * 12 + i] : sw[(n * 12 + i) * 4 + f - 1];
    }
    Wf1[t] = (_Float16)val;
}

// ---------- conv1 as fp16 MFMA GEMM + fused raw maxpool + stats ----------
// M-order: interior patches grouped so the 4 cells of a pool window are 4
// consecutive rows (m = ((b*225+cell)*4 + pp)); border patches (py==30 or
// px==30, stats only) appended as blocks 14400..15375. Each wave owns 16
// rows: lane (vg=lane>>4, rl=lane&15) expands 3 window values (15 fp16 + pad)
// into Eh row rl; same-wave in-order LDS makes write->read barrier-free
// (pattern validated in conv2). C layout row=quad*4+reg puts one pool window
// in one lane's 4 acc regs -> in-register maxpool, coalesced pooled store.

#define E_LDW 72  // 64 halves data + 8 pad (144B row stride: bank-friendly)

__global__ __launch_bounds__(256, 8) void conv1_kernel(
        const float* __restrict__ x, const _Float16* __restrict__ Wf1,
        float* __restrict__ pooled, float* __restrict__ part) {
    __shared__ _Float16 Eh[64 * E_LDW];
    __shared__ float Rs[4][64];

    int t = threadIdx.x;
    int lane = t & 63, wv = t >> 6;
    int rl = lane & 15, vg = lane >> 4;
    int l15 = rl, quad = vg;

    bool interior = blockIdx.x < 14400;
    int b, py, px;
    if (interior) {
        int mrow = blockIdx.x * 64 + wv * 16 + rl;
        int g4 = mrow >> 2, pp = mrow & 3;
        b = g4 / 225;
        int cell = g4 - b * 225;
        int pm = cell / 15, pn = cell - pm * 15;
        py = 2 * pm + (pp >> 1);
        px = 2 * pn + (pp & 1);
    } else {
        int j = (blockIdx.x - 14400) * 64 + wv * 16 + rl;
        b = j / 61;
        int r = j - b * 61;
        py = (r < 31) ? 30 : (r - 31);
        px = (r < 31) ? r : 30;
    }

    // ---- expand this lane's 3 window values -> 15 fp16 + zero pad ----
    float fv[16];
    fv[15] = 0.f;
#pragma unroll
    for (int q = 0; q < 3; ++q) {
        int i = vg * 3 + q;
        int c = i >> 2, dy = (i >> 1) & 1, dx = i & 1;
        float v = x[((size_t)(b * 3 + c)) * 1024 + (py + dy) * 32 + (px + dx)];
        fv[q * 5] = siluf(v);
        bspline4(v, &fv[q * 5 + 1]);
    }
    int* dst = (int*)&Eh[(wv * 16 + rl) * E_LDW + vg * 16];
#pragma unroll
    for (int k2 = 0; k2 < 8; ++k2) {
        union { _Float16 h[2]; int i32; } p;
        p.h[0] = (_Float16)fv[2 * k2];
        p.h[1] = (_Float16)fv[2 * k2 + 1];
        dst[k2] = p.i32;
    }

    // ---- MFMA: 16 patches x 32 outputs, K=64 (no barrier: same-wave LDS) ----
    f32x4 acc[2];
    acc[0] = (f32x4){0.f, 0.f, 0.f, 0.f};
    acc[1] = (f32x4){0.f, 0.f, 0.f, 0.f};
    const _Float16* Ew = &Eh[(wv * 16 + l15) * E_LDW + quad * 8];
#pragma unroll
    for (int ks = 0; ks < 2; ++ks) {
        f16x8 a = *(const f16x8*)(Ew + ks * 32);
#pragma unroll
        for (int nt = 0; nt < 2; ++nt) {
            f16x8 bf = *(const f16x8*)&Wf1[(size_t)(nt * 16 + l15) * 64
                                           + ks * 32 + quad * 8];
            acc[nt] = __builtin_amdgcn_mfma_f32_16x16x32_f16(a, bf, acc[nt], 0, 0, 0);
        }
    }

    // ---- pooled write (interior): lane's 4 regs = one pool window ----
    if (interior) {
        int g4 = blockIdx.x * 16 + wv * 4 + quad;
        float* dp = pooled + (size_t)g4 * 32 + l15;
        dp[0]  = fmaxf(fmaxf(acc[0][0], acc[0][1]), fmaxf(acc[0][2], acc[0][3]));
        dp[16] = fmaxf(fmaxf(acc[1][0], acc[1][1]), fmaxf(acc[1][2], acc[1][3]));
    }

    // ---- stats: per-lane 4-row sums, reduce across quads, then waves ----
    float s0 = acc[0][0] + acc[0][1] + acc[0][2] + acc[0][3];
    float q0 = acc[0][0] * acc[0][0] + acc[0][1] * acc[0][1]
             + acc[0][2] * acc[0][2] + acc[0][3] * acc[0][3];
    float s1 = acc[1][0] + acc[1][1] + acc[1][2] + acc[1][3];
    float q1 = acc[1][0] * acc[1][0] + acc[1][1] * acc[1][1]
             + acc[1][2] * acc[1][2] + acc[1][3] * acc[1][3];
    s0 += __shfl_down(s0, 32, 64); s0 += __shfl_down(s0, 16, 64);
    q0 += __shfl_down(q0, 32, 64); q0 += __shfl_down(q0, 16, 64);
    s1 += __shfl_down(s1, 32, 64); s1 += __shfl_down(s1, 16, 64);
    q1 += __shfl_down(q1, 32, 64); q1 += __shfl_down(q1, 16, 64);
    if (lane < 16) {
        Rs[wv][2 * l15]          = s0;
        Rs[wv][2 * l15 + 1]      = q0;
        Rs[wv][32 + 2 * l15]     = s1;
        Rs[wv][32 + 2 * l15 + 1] = q1;
    }
    __syncthreads();
    if (t < 64)
        part[(size_t)t * NSLOT1 + blockIdx.x] =
            Rs[0][t] + Rs[1][t] + Rs[2][t] + Rs[3][t];
}

// ---------- pre-convert conv2 weights to f16, k-layout = c*20 + s*5 + f ----------

__global__ __launch_bounds__(256) void wconv16_kernel(
        const float* __restrict__ bw, const float* __restrict__ sw,
        _Float16* __restrict__ Wf) {
    int t = blockIdx.x * 256 + threadIdx.x;
    if (t >= 64 * 640) return;
    int n = t / 640;
    int k = t - n * 640;
    int c = k / 20;
    int r = k - c * 20;
    int s = r / 5;
    int f = r - s * 5;
    float val = (f == 0) ? bw[n * 128 + c * 4 + s]
                         : sw[n * 512 + c * 16 + s * 4 + (f - 1)];
    Wf[t] = (_Float16)val;
}

// ---------- conv2 group-data prefetch ----------

__device__ __forceinline__ void c2_load(
        const float* __restrict__ pooled, const float* __restrict__ stats1,
        const float* __restrict__ g1v, const float* __restrict__ b1v,
        int c, const size_t pwoff[2], float pv[2][4], float pst[4]) {
    pst[0] = stats1[2 * c];
    pst[1] = stats1[2 * c + 1];
    pst[2] = g1v[c];
    pst[3] = b1v[c];
#pragma unroll
    for (int cc = 0; cc < 2; ++cc) {
        const float* pw = pooled + pwoff[cc] + c;
        pv[cc][0] = pw[0];
        pv[cc][1] = pw[32];
        pv[cc][2] = pw[480];
        pv[cc][3] = pw[512];
    }
}

// ---------- conv2 (fp16 MFMA, barrier-free, single-buffer, pipelined) ----------

#define C2_LDW 168

__global__ __launch_bounds__(256, 5) void conv2_kernel(
        const float* __restrict__ pooled, const float* __restrict__ stats1,
        const float* __restrict__ g1v, const float* __restrict__ b1v,
        const _Float16* __restrict__ Wf, float* __restrict__ Pt,
        float* __restrict__ part) {
    __shared__ _Float16 Eh[64 * C2_LDW];

    int t = threadIdx.x;
    int lane = t & 63, wv = t >> 6;
    int quad = lane >> 4, l15 = lane & 15;

    int cl = lane & 7;           // channel within group (8 per group)
    int rl = lane >> 3;          // 0..7; rows rl and rl+8 of this wave's tile
    int m[2];
    size_t pwoff[2];
#pragma unroll
    for (int cc = 0; cc < 2; ++cc) {
        m[cc] = wv * 16 + rl + 8 * cc;
        int patch = blockIdx.x * 64 + m[cc];
        int pb = patch / 196;
        int q = patch - pb * 196;
        int py = q / 14;
        int px = q - py * 14;
        pwoff[cc] = ((size_t)pb * 225 + py * 15 + px) * 32;
    }
    const float invN1 = 1.0f / (1024.0f * 961.0f);

    f32x4 acc[4];
#pragma unroll
    for (int nt = 0; nt < 4; ++nt) acc[nt] = (f32x4){0.f, 0.f, 0.f, 0.f};

    float pv[2][4], pst[4];
    c2_load(pooled, stats1, g1v, b1v, cl, pwoff, pv, pst);

#pragma unroll 1
    for (int g = 0; g < 4; ++g) {
        float mean = pst[0] * invN1;
        float var  = pst[1] * invN1 - mean * mean;
        float sc = rsqrtf(var + BN_EPS) * pst[2];
        float sh = pst[3] - mean * sc;
        float cv[2][4];
#pragma unroll
        for (int cc = 0; cc < 2; ++cc)
#pragma unroll
            for (int s = 0; s < 4; ++s)
                cv[cc][s] = fmaxf(pv[cc][s] * sc + sh, 0.f);
        // prefetch next group's pooled/BN data (uses are next iteration)
        if (g < 3)
            c2_load(pooled, stats1, g1v, b1v, (g + 1) * 8 + cl, pwoff, pv, pst);
        // ---- build this wave's 16 E rows (fp16), 2 cells per lane ----
#pragma unroll
        for (int cc = 0; cc < 2; ++cc) {
            float f[20];
#pragma unroll
            for (int s = 0; s < 4; ++s) {
                float v = cv[cc][s];
                f[s * 5] = siluf(v);
                bspline4(v, &f[s * 5 + 1]);
            }
            int* dst = (int*)&Eh[m[cc] * C2_LDW + cl * 20];
#pragma unroll
            for (int i = 0; i < 10; ++i) {
                union { _Float16 h[2]; int i32; } u;
                u.h[0] = (_Float16)f[2 * i];
                u.h[1] = (_Float16)f[2 * i + 1];
                dst[i] = u.i32;
            }
        }
        // ---- MFMA (no barrier: rows wv*16..+15 written by this wave) ----
#pragma unroll
        for (int ks = 0; ks < 5; ++ks) {
            int ko = ks * 32 + quad * 8;
            f16x8 a = *(const f16x8*)&Eh[(wv * 16 + l15) * C2_LDW + ko];
#pragma unroll
            for (int nt = 0; nt < 4; ++nt) {
                f16x8 bf = *(const f16x8*)&Wf[(size_t)(nt * 16 + l15) * 640
                                              + g * 160 + ko];
                acc[nt] = __builtin_amdgcn_mfma_f32_16x16x32_f16(a, bf, acc[nt], 0, 0, 0);
            }
        }
    }

    // ---- store: rows wv*16 + quad*4 + reg, cols nt*16 + l15 ----
    int rowb = blockIdx.x * 64 + wv * 16 + quad * 4;
#pragma unroll
    for (int nt = 0; nt < 4; ++nt) {
        int o = nt * 16 + l15;
#pragma unroll
        for (int reg = 0; reg < 4; ++reg)
            Pt[(size_t)(rowb + reg) * 64 + o] = acc[nt][reg];
    }
    // ---- fused stats over this wave's 16 rows ----
    float s[4], s2[4];
#pragma unroll
    for (int nt = 0; nt < 4; ++nt) {
        float a0 = acc[nt][0], a1 = acc[nt][1], a2v = acc[nt][2], a3 = acc[nt][3];
        s[nt]  = a0 + a1 + a2v + a3;
        s2[nt] = a0 * a0 + a1 * a1 + a2v * a2v + a3 * a3;
    }
#pragma unroll
    for (int nt = 0; nt < 4; ++nt) {
        s[nt]  += __shfl_down(s[nt], 16, 64);
        s2[nt] += __shfl_down(s2[nt], 16, 64);
        s[nt]  += __shfl_down(s[nt], 32, 64);
        s2[nt] += __shfl_down(s2[nt], 32, 64);
    }
    if (lane < 16) {
        int slot = blockIdx.x * 4 + wv;
#pragma unroll
        for (int nt = 0; nt < 4; ++nt) {
            int o = nt * 16 + l15;
            part[(size_t)(2 * o) * NSLOT2 + slot]     = s[nt];
            part[(size_t)(2 * o + 1) * NSLOT2 + slot] = s2[nt];
        }
    }
}

// ---------- reduce per-wave partials -> stats ----------

__global__ __launch_bounds__(256) void redstats_kernel(
        const float* __restrict__ part, float* __restrict__ stats, int nblk) {
    int p = blockIdx.x;
    const float* src = part + (size_t)p * nblk;
    float s = 0.f;
    for (int j = threadIdx.x; j < nblk; j += 256) s += src[j];
#pragma unroll
    for (int off = 32; off > 0; off >>= 1) s += __shfl_down(s, off, 64);
    __shared__ float ls[4];
    if ((threadIdx.x & 63) == 0) ls[threadIdx.x >> 6] = s;
    __syncthreads();
    if (threadIdx.x == 0) stats[p] = ls[0] + ls[1] + ls[2] + ls[3];
}

// ---------- stage-2 BN + ReLU + pool from Pt [patch][64] -> pooled2 [b][q2*64+c] ----------

__global__ __launch_bounds__(256) void bnpool2_kernel(
        const float* __restrict__ Pt, const float* __restrict__ stats,
        const float* __restrict__ g, const float* __restrict__ bb,
        float* __restrict__ out) {
    int t = blockIdx.x * 256 + threadIdx.x;
    if (t >= 1024 * 49 * 64) return;
    int c  = t & 63;
    int q2 = (t >> 6) % 49;
    int b  = t / (49 * 64);
    float mean = stats[2 * c] * (1.0f / 200704.0f);
    float var  = stats[2 * c + 1] * (1.0f / 200704.0f) - mean * mean;
    float sc = rsqrtf(var + BN_EPS) * g[c];
    float sh = bb[c] - mean * sc;
    int py2 = q2 / 7, px2 = q2 - py2 * 7;
    int q = (py2 * 2) * 14 + px2 * 2;
    const float* p = Pt + ((size_t)b * 196 + q) * 64 + c;
    float v0 = fmaxf(p[0] * sc + sh, 0.f);
    float v1 = fmaxf(p[64] * sc + sh, 0.f);
    float v2 = fmaxf(p[14 * 64] * sc + sh, 0.f);
    float v3 = fmaxf(p[15 * 64] * sc + sh, 0.f);
    out[t] = fmaxf(fmaxf(v0, v1), fmaxf(v2, v3));
}

// ---------- transpose fc1_w into wT[(q2*64 + c)*64 + o] ----------

__global__ __launch_bounds__(256) void transpose_kernel(
        const float* __restrict__ w, float* __restrict__ wT) {
    int t = blockIdx.x * 256 + threadIdx.x;
    if (t >= 64 * 3136) return;
    int o = t & 63;
    int m = t >> 6;
    int c = m & 63;
    int q2 = m >> 6;
    wT[(size_t)m * 64 + o] = w[(size_t)o * 3136 + c * 49 + q2];
}

// ---------- fc1: pooled2 flat [1024,3136] @ wT -> z [1024,64] ----------

__global__ __launch_bounds__(256) void fc1_kernel(
        const float* __restrict__ xin, const float* __restrict__ wT,
        const float* __restrict__ bias, float* __restrict__ z) {
    __shared__ float xs[4 * 3136];
    __shared__ float red[4][4][64];
    int b0 = blockIdx.x * 4;
    for (int j = threadIdx.x; j < 4 * 3136; j += 256)
        xs[j] = xin[(size_t)b0 * 3136 + j];
    __syncthreads();
    int o = threadIdx.x & 63, q = threadIdx.x >> 6;
    float s0 = 0.f, s1 = 0.f, s2 = 0.f, s3 = 0.f;
    for (int j = q * 784; j < q * 784 + 784; ++j) {
        float wv = wT[(size_t)j * 64 + o];
        s0 += xs[j] * wv;
        s1 += xs[3136 + j] * wv;
        s2 += xs[2 * 3136 + j] * wv;
        s3 += xs[3 * 3136 + j] * wv;
    }
    red[0][q][o] = s0; red[1][q][o] = s1; red[2][q][o] = s2; red[3][q][o] = s3;
    __syncthreads();
    int bb = threadIdx.x >> 6;
    float tot = red[bb][0][o] + red[bb][1][o] + red[bb][2][o] + red[bb][3][o] + bias[o];
    z[((size_t)(b0 + bb)) * 64 + o] = tot;
}

// ---------- bn1d column stats over z [1024,64] ----------

__global__ __launch_bounds__(256) void colstats_kernel(
        const float* __restrict__ z, float* __restrict__ stats) {
    int c = blockIdx.x;
    float s = 0.f, s2 = 0.f;
    for (int b = threadIdx.x; b < 1024; b += 256) {
        float v = z[(size_t)b * 64 + c];
        s += v; s2 += v * v;
    }
#pragma unroll
    for (int off = 32; off > 0; off >>= 1) {
        s  += __shfl_down(s, off, 64);
        s2 += __shfl_down(s2, off, 64);
    }
    __shared__ float ls[8];
    int w = threadIdx.x >> 6;
    if ((threadIdx.x & 63) == 0) { ls[w * 2] = s; ls[w * 2 + 1] = s2; }
    __syncthreads();
    if (threadIdx.x == 0) {
        stats[2 * c]     = ls[0] + ls[2] + ls[4] + ls[6];
        stats[2 * c + 1] = ls[1] + ls[3] + ls[5] + ls[7];
    }
}

// ---------- final: bn1d + relu + fc2 -> out [1024,10] ----------

__global__ __launch_bounds__(256) void final_kernel(
        const float* __restrict__ z, const float* __restrict__ stats,
        const float* __restrict__ g, const float* __restrict__ bb,
        const float* __restrict__ w2, const float* __restrict__ b2,
        float* __restrict__ out) {
    int t = blockIdx.x * 256 + threadIdx.x;
    if (t >= 10240) return;
    int o = t % 10, b = t / 10;
    float acc = b2[o];
#pragma unroll 8
    for (int c = 0; c < 64; ++c) {
        float mean = stats[2 * c] * (1.0f / 1024.0f);
        float var  = stats[2 * c + 1] * (1.0f / 1024.0f) - mean * mean;
        float sc = rsqrtf(var + BN_EPS) * g[c];
        float a = fmaxf(z[(size_t)b * 64 + c] * sc + (bb[c] - mean * sc), 0.f);
        acc += a * w2[o * 64 + c];
    }
    out[t] = acc;
}

// ---------- launch ----------

extern "C" void kernel_launch(void* const* d_in, const int* in_sizes, int n_in,
                              void* d_out, int out_size, void* d_ws, size_t ws_size,
                              hipStream_t stream) {
    const float* x   = (const float*)d_in[0];
    const float* bw1 = (const float*)d_in[1];
    const float* sw1 = (const float*)d_in[2];
    const float* g1  = (const float*)d_in[3];
    const float* b1  = (const float*)d_in[4];
    const float* bw2 = (const float*)d_in[5];
    const float* sw2 = (const float*)d_in[6];
    const float* g2  = (const float*)d_in[7];
    const float* b2v = (const float*)d_in[8];
    const float* fw1 = (const float*)d_in[9];
    const float* fb1 = (const float*)d_in[10];
    const float* g3  = (const float*)d_in[11];
    const float* b3  = (const float*)d_in[12];
    const float* fw2 = (const float*)d_in[13];
    const float* fb2 = (const float*)d_in[14];
    float* out = (float*)d_out;

    char* ws = (char*)d_ws;
    // region A [0, 58 MB): part1 (3.94 MB) during conv1 (dead after redstats1),
    //   then Pt [200704][64] (51.38 MB) + part2 at +51,380,224 (6.4 MB)
    float* part1  = (float*)(ws);
    float* Pt     = (float*)(ws);
    float* part2  = (float*)(ws + 51380224);
    // Wf (80 KB) + Wf1 (4 KB) in the dead gap between region A and region B
    _Float16* Wf  = (_Float16*)(ws + 100000000);
    _Float16* Wf1 = (_Float16*)(ws + 100131072);
    // region B: pooled raw [1024][225][32] (29.5 MB); later pooled2 [1024,3136]
    float* pooled = (float*)(ws + 125960192);
    float* z      = (float*)(ws + 155451392);   // [1024,64]
    float* wT     = (float*)(ws + 155713536);   // [3136,64]
    float* stats1 = (float*)(ws + 156516352);   // 64 floats
    float* stats2 = (float*)(ws + 156516608);   // 128 floats
    float* stats3 = (float*)(ws + 156517120);   // 128 floats

    transpose_kernel<<<(64 * 3136 + 255) / 256, 256, 0, stream>>>(fw1, wT);
    wconv16_kernel<<<160, 256, 0, stream>>>(bw2, sw2, Wf);
    wconv1h_kernel<<<8, 256, 0, stream>>>(bw1, sw1, Wf1);

    conv1_kernel<<<15376, 256, 0, stream>>>(x, Wf1, pooled, part1);
    redstats_kernel<<<64, 256, 0, stream>>>(part1, stats1, NSLOT1);

    conv2_kernel<<<3136, 256, 0, stream>>>(pooled, stats1, g1, b1,
                                           Wf, Pt, part2);
    redstats_kernel<<<128, 256, 0, stream>>>(part2, stats2, NSLOT2);

    float* pooled2 = pooled;  // region B reuse (pooled raw dead after conv2)
    bnpool2_kernel<<<(1024 * 49 * 64 + 255) / 256, 256, 0, stream>>>(
        Pt, stats2, g2, b2v, pooled2);

    fc1_kernel<<<256, 256, 0, stream>>>(pooled2, wT, fb1, z);
    colstats_kernel<<<64, 256, 0, stream>>>(z, stats3);
    final_kernel<<<(10240 + 255) / 256, 256, 0, stream>>>(z, stats3, g3, b3, fw2, fb2, out);
}

// Round 3
// 352.950 us; speedup vs baseline: 1.3761x; 1.0288x over previous
//
#include <hip/hip_runtime.h>
#include <math.h>

#define BN_EPS 1e-5f
#define NSLOT1 15376  // conv1: one slot per block (14400 interior + 976 border)
#define NSLOT2 12544  // conv2 3136*4

typedef __attribute__((ext_vector_type(8))) _Float16 f16x8;
typedef __attribute__((ext_vector_type(2))) __fp16 fp16v2;
typedef __attribute__((ext_vector_type(4))) float f32x4;

// ---------- helpers ----------

__device__ __forceinline__ float siluf(float v) {
    // fast rcp instead of precise divide (~1 ulp, fine vs fp16 downstream)
    return v * __builtin_amdgcn_rcpf(1.0f + __expf(-v));
}

// 6*basis_i(x), i=0..3, cubic B-spline on knots g[j]=2j-7.
// 6*B(t) = max(0,2-|t|)^3 - 4*max(0,1-|t|)^3 with t = u-(i+2), u=(x+7)/2.
// The 1/6 is folded into the spline weights at prep time. Branchless,
// no int convert, 4 independent FMA-pipe chains (vs 32-op cndmask scatter).
__device__ __forceinline__ void expand5(float v, float f[5]) {
    f[0] = siluf(v);
    float u = (v + 7.0f) * 0.5f;
#pragma unroll
    for (int i = 0; i < 4; ++i) {
        float a = fabsf(u - (float)(i + 2));
        float p = fmaxf(2.0f - a, 0.0f);
        float q = fmaxf(1.0f - a, 0.0f);
        f[i + 1] = p * p * p - 4.0f * (q * q * q);
    }
}

__device__ __forceinline__ int pkh(float a, float b) {
    union { fp16v2 h2; int i; } u;
    u.h2 = __builtin_amdgcn_cvt_pkrtz(a, b);
    return u.i;
}

// ---------- pre-convert conv1 weights to f16 (spline weights scaled 1/6) ----------
// K layout: k = g*16 + ql*5 + f for value i = g*3+ql (i = c*4+dy*2+dx), f=0..4

__global__ __launch_bounds__(256) void wconv1h_kernel(
        const float* __restrict__ bw, const float* __restrict__ sw,
        _Float16* __restrict__ Wf1) {
    int t = blockIdx.x * 256 + threadIdx.x;
    if (t >= 32 * 64) return;
    int n = t >> 6;
    int k = t & 63;
    int g = k >> 4, loc = k & 15;
    float val = 0.f;
    if (loc < 15) {
        int ql = loc / 5, f = loc - ql * 5;
        int i = g * 3 + ql;
        val = (f == 0) ? bw[n * 12 + i]
                       : sw[(n * 12 + i) * 4 + f - 1] * (1.0f / 6.0f);
    }
    Wf1[t] = (_Float16)val;
}

// ---------- conv1 as fp16 MFMA GEMM + fused raw maxpool + stats ----------

#define E_LDW 74  // 64 halves data + 10 pad (148B stride: odd dword step, no bank clash)

__global__ __launch_bounds__(256, 8) void conv1_kernel(
        const float* __restrict__ x, const _Float16* __restrict__ Wf1,
        float* __restrict__ pooled, float* __restrict__ part) {
    __shared__ _Float16 Eh[64 * E_LDW];
    __shared__ float Rs[4][64];

    int t = threadIdx.x;
    int lane = t & 63, wv = t >> 6;
    int rl = lane & 15, vg = lane >> 4;
    int l15 = rl, quad = vg;

    bool interior = blockIdx.x < 14400;
    int b, py, px;
    if (interior) {
        int mrow = blockIdx.x * 64 + wv * 16 + rl;
        int g4 = mrow >> 2, pp = mrow & 3;
        b = g4 / 225;
        int cell = g4 - b * 225;
        int pm = cell / 15, pn = cell - pm * 15;
        py = 2 * pm + (pp >> 1);
        px = 2 * pn + (pp & 1);
    } else {
        int j = (blockIdx.x - 14400) * 64 + wv * 16 + rl;
        b = j / 61;
        int r = j - b * 61;
        py = (r < 31) ? 30 : (r - 31);
        px = (r < 31) ? r : 30;
    }

    // ---- expand this lane's 3 window values -> 15 fp16 + zero pad ----
    float fv[16];
    fv[15] = 0.f;
#pragma unroll
    for (int q = 0; q < 3; ++q) {
        int i = vg * 3 + q;
        int c = i >> 2, dy = (i >> 1) & 1, dx = i & 1;
        float v = x[((size_t)(b * 3 + c)) * 1024 + (py + dy) * 32 + (px + dx)];
        expand5(v, &fv[q * 5]);
    }
    int* dst = (int*)&Eh[(wv * 16 + rl) * E_LDW + vg * 16];
#pragma unroll
    for (int k2 = 0; k2 < 8; ++k2) dst[k2] = pkh(fv[2 * k2], fv[2 * k2 + 1]);

    // ---- MFMA: 16 patches x 32 outputs, K=64 (no barrier: same-wave LDS) ----
    f32x4 acc[2];
    acc[0] = (f32x4){0.f, 0.f, 0.f, 0.f};
    acc[1] = (f32x4){0.f, 0.f, 0.f, 0.f};
    const _Float16* Ew = &Eh[(wv * 16 + l15) * E_LDW + quad * 8];
#pragma unroll
    for (int ks = 0; ks < 2; ++ks) {
        f16x8 a = *(const f16x8*)(Ew + ks * 32);
#pragma unroll
        for (int nt = 0; nt < 2; ++nt) {
            f16x8 bf = *(const f16x8*)&Wf1[(size_t)(nt * 16 + l15) * 64
                                           + ks * 32 + quad * 8];
            acc[nt] = __builtin_amdgcn_mfma_f32_16x16x32_f16(a, bf, acc[nt], 0, 0, 0);
        }
    }

    // ---- pooled write (interior): lane's 4 regs = one pool window ----
    if (interior) {
        int g4 = blockIdx.x * 16 + wv * 4 + quad;
        float* dp = pooled + (size_t)g4 * 32 + l15;
        dp[0]  = fmaxf(fmaxf(acc[0][0], acc[0][1]), fmaxf(acc[0][2], acc[0][3]));
        dp[16] = fmaxf(fmaxf(acc[1][0], acc[1][1]), fmaxf(acc[1][2], acc[1][3]));
    }

    // ---- stats: per-lane 4-row sums, reduce across quads, then waves ----
    float s0 = acc[0][0] + acc[0][1] + acc[0][2] + acc[0][3];
    float q0 = acc[0][0] * acc[0][0] + acc[0][1] * acc[0][1]
             + acc[0][2] * acc[0][2] + acc[0][3] * acc[0][3];
    float s1 = acc[1][0] + acc[1][1] + acc[1][2] + acc[1][3];
    float q1 = acc[1][0] * acc[1][0] + acc[1][1] * acc[1][1]
             + acc[1][2] * acc[1][2] + acc[1][3] * acc[1][3];
    s0 += __shfl_down(s0, 32, 64); s0 += __shfl_down(s0, 16, 64);
    q0 += __shfl_down(q0, 32, 64); q0 += __shfl_down(q0, 16, 64);
    s1 += __shfl_down(s1, 32, 64); s1 += __shfl_down(s1, 16, 64);
    q1 += __shfl_down(q1, 32, 64); q1 += __shfl_down(q1, 16, 64);
    if (lane < 16) {
        Rs[wv][2 * l15]          = s0;
        Rs[wv][2 * l15 + 1]      = q0;
        Rs[wv][32 + 2 * l15]     = s1;
        Rs[wv][32 + 2 * l15 + 1] = q1;
    }
    __syncthreads();
    if (t < 64)
        part[(size_t)t * NSLOT1 + blockIdx.x] =
            Rs[0][t] + Rs[1][t] + Rs[2][t] + Rs[3][t];
}

// ---------- pre-convert conv2 weights to f16 (spline weights scaled 1/6) ----------

__global__ __launch_bounds__(256) void wconv16_kernel(
        const float* __restrict__ bw, const float* __restrict__ sw,
        _Float16* __restrict__ Wf) {
    int t = blockIdx.x * 256 + threadIdx.x;
    if (t >= 64 * 640) return;
    int n = t / 640;
    int k = t - n * 640;
    int c = k / 20;
    int r = k - c * 20;
    int s = r / 5;
    int f = r - s * 5;
    float val = (f == 0) ? bw[n * 128 + c * 4 + s]
                         : sw[n * 512 + c * 16 + s * 4 + (f - 1)] * (1.0f / 6.0f);
    Wf[t] = (_Float16)val;
}

// ---------- conv2 helpers ----------

#define C2_LDW 170  // 160 halves data + 10 pad (340B stride: odd dword step)

__device__ __forceinline__ void c2_load(
        const float* __restrict__ pooled, const float* __restrict__ stats1,
        const float* __restrict__ g1v, const float* __restrict__ b1v,
        int c, const size_t pwoff[2], float pv[2][4], float pst[4]) {
    pst[0] = stats1[2 * c];
    pst[1] = stats1[2 * c + 1];
    pst[2] = g1v[c];
    pst[3] = b1v[c];
#pragma unroll
    for (int cc = 0; cc < 2; ++cc) {
        const float* pw = pooled + pwoff[cc] + c;
        pv[cc][0] = pw[0];
        pv[cc][1] = pw[32];
        pv[cc][2] = pw[480];
        pv[cc][3] = pw[512];
    }
}

__device__ __forceinline__ void c2_expand(
        const float pv[2][4], const float pst[4], int ew[2][10]) {
    const float invN1 = 1.0f / (1024.0f * 961.0f);
    float mean = pst[0] * invN1;
    float var  = pst[1] * invN1 - mean * mean;
    float sc = rsqrtf(var + BN_EPS) * pst[2];
    float sh = pst[3] - mean * sc;
#pragma unroll
    for (int cc = 0; cc < 2; ++cc) {
        float f[20];
#pragma unroll
        for (int s = 0; s < 4; ++s) {
            float v = fmaxf(pv[cc][s] * sc + sh, 0.f);
            expand5(v, &f[s * 5]);
        }
#pragma unroll
        for (int i = 0; i < 10; ++i) ew[cc][i] = pkh(f[2 * i], f[2 * i + 1]);
    }
}

__device__ __forceinline__ void c2_write(
        _Float16* Eh, const int m[2], int cl, const int ew[2][10]) {
#pragma unroll
    for (int cc = 0; cc < 2; ++cc) {
        int* dst = (int*)&Eh[m[cc] * C2_LDW + cl * 20];
#pragma unroll
        for (int i = 0; i < 10; ++i) dst[i] = ew[cc][i];
    }
}

__device__ __forceinline__ void c2_mfma(
        const _Float16* Eh, const _Float16* __restrict__ Wf,
        int wv, int l15, int quad, int g, f32x4 acc[4]) {
#pragma unroll
    for (int ks = 0; ks < 5; ++ks) {
        int ko = ks * 32 + quad * 8;
        f16x8 a = *(const f16x8*)&Eh[(wv * 16 + l15) * C2_LDW + ko];
#pragma unroll
        for (int nt = 0; nt < 4; ++nt) {
            f16x8 bf = *(const f16x8*)&Wf[(size_t)(nt * 16 + l15) * 640
                                          + g * 160 + ko];
            acc[nt] = __builtin_amdgcn_mfma_f32_16x16x32_f16(a, bf, acc[nt], 0, 0, 0);
        }
    }
}

// ---------- conv2 (fp16 MFMA, barrier-free, software-pipelined) ----------
// Per-group phase order: load(g+2) -> expand(g+1) -> MFMA(g) -> ds_write(g+1).
// Global-load latency and the ds_write->ds_read turnaround both hide under a
// full expansion+MFMA phase. Single Eh buffer stays safe: each wave reads only
// rows it wrote; same-wave in-order LDS preserves the WAR ordering.

__global__ __launch_bounds__(256, 7) void conv2_kernel(
        const float* __restrict__ pooled, const float* __restrict__ stats1,
        const float* __restrict__ g1v, const float* __restrict__ b1v,
        const _Float16* __restrict__ Wf, float* __restrict__ Pt,
        float* __restrict__ part) {
    __shared__ _Float16 Eh[64 * C2_LDW];

    int t = threadIdx.x;
    int lane = t & 63, wv = t >> 6;
    int quad = lane >> 4, l15 = lane & 15;

    int cl = lane & 7;           // channel within group (8 per group)
    int rl = lane >> 3;          // 0..7; rows rl and rl+8 of this wave's tile
    int m[2];
    size_t pwoff[2];
#pragma unroll
    for (int cc = 0; cc < 2; ++cc) {
        m[cc] = wv * 16 + rl + 8 * cc;
        int patch = blockIdx.x * 64 + m[cc];
        int pb = patch / 196;
        int q = patch - pb * 196;
        int py = q / 14;
        int px = q - py * 14;
        pwoff[cc] = ((size_t)pb * 225 + py * 15 + px) * 32;
    }

    f32x4 acc[4];
#pragma unroll
    for (int nt = 0; nt < 4; ++nt) acc[nt] = (f32x4){0.f, 0.f, 0.f, 0.f};

    float pvA[2][4], pstA[4], pvB[2][4], pstB[4];
    int ew[2][10];

    // prologue: issue loads for groups 0,1; expand+write group 0
    c2_load(pooled, stats1, g1v, b1v, cl, pwoff, pvA, pstA);
    c2_load(pooled, stats1, g1v, b1v, 8 + cl, pwoff, pvB, pstB);
    c2_expand(pvA, pstA, ew);
    c2_write(Eh, m, cl, ew);

    // g = 0
    c2_load(pooled, stats1, g1v, b1v, 16 + cl, pwoff, pvA, pstA);
    c2_expand(pvB, pstB, ew);
    c2_mfma(Eh, Wf, wv, l15, quad, 0, acc);
    c2_write(Eh, m, cl, ew);
    // g = 1
    c2_load(pooled, stats1, g1v, b1v, 24 + cl, pwoff, pvB, pstB);
    c2_expand(pvA, pstA, ew);
    c2_mfma(Eh, Wf, wv, l15, quad, 1, acc);
    c2_write(Eh, m, cl, ew);
    // g = 2
    c2_expand(pvB, pstB, ew);
    c2_mfma(Eh, Wf, wv, l15, quad, 2, acc);
    c2_write(Eh, m, cl, ew);
    // g = 3
    c2_mfma(Eh, Wf, wv, l15, quad, 3, acc);

    // ---- store: rows wv*16 + quad*4 + reg, cols nt*16 + l15 ----
    int rowb = blockIdx.x * 64 + wv * 16 + quad * 4;
#pragma unroll
    for (int nt = 0; nt < 4; ++nt) {
        int o = nt * 16 + l15;
#pragma unroll
        for (int reg = 0; reg < 4; ++reg)
            Pt[(size_t)(rowb + reg) * 64 + o] = acc[nt][reg];
    }
    // ---- fused stats over this wave's 16 rows ----
    float s[4], s2[4];
#pragma unroll
    for (int nt = 0; nt < 4; ++nt) {
        float a0 = acc[nt][0], a1 = acc[nt][1], a2v = acc[nt][2], a3 = acc[nt][3];
        s[nt]  = a0 + a1 + a2v + a3;
        s2[nt] = a0 * a0 + a1 * a1 + a2v * a2v + a3 * a3;
    }
#pragma unroll
    for (int nt = 0; nt < 4; ++nt) {
        s[nt]  += __shfl_down(s[nt], 16, 64);
        s2[nt] += __shfl_down(s2[nt], 16, 64);
        s[nt]  += __shfl_down(s[nt], 32, 64);
        s2[nt] += __shfl_down(s2[nt], 32, 64);
    }
    if (lane < 16) {
        int slot = blockIdx.x * 4 + wv;
#pragma unroll
        for (int nt = 0; nt < 4; ++nt) {
            int o = nt * 16 + l15;
            part[(size_t)(2 * o) * NSLOT2 + slot]     = s[nt];
            part[(size_t)(2 * o + 1) * NSLOT2 + slot] = s2[nt];
        }
    }
}

// ---------- reduce per-wave partials -> stats ----------

__global__ __launch_bounds__(256) void redstats_kernel(
        const float* __restrict__ part, float* __restrict__ stats, int nblk) {
    int p = blockIdx.x;
    const float* src = part + (size_t)p * nblk;
    float s = 0.f;
    for (int j = threadIdx.x; j < nblk; j += 256) s += src[j];
#pragma unroll
    for (int off = 32; off > 0; off >>= 1) s += __shfl_down(s, off, 64);
    __shared__ float ls[4];
    if ((threadIdx.x & 63) == 0) ls[threadIdx.x >> 6] = s;
    __syncthreads();
    if (threadIdx.x == 0) stats[p] = ls[0] + ls[1] + ls[2] + ls[3];
}

// ---------- stage-2 BN + ReLU + pool from Pt [patch][64] -> pooled2 [b][q2*64+c] ----------

__global__ __launch_bounds__(256) void bnpool2_kernel(
        const float* __restrict__ Pt, const float* __restrict__ stats,
        const float* __restrict__ g, const float* __restrict__ bb,
        float* __restrict__ out) {
    int t = blockIdx.x * 256 + threadIdx.x;
    if (t >= 1024 * 49 * 64) return;
    int c  = t & 63;
    int q2 = (t >> 6) % 49;
    int b  = t / (49 * 64);
    float mean = stats[2 * c] * (1.0f / 200704.0f);
    float var  = stats[2 * c + 1] * (1.0f / 200704.0f) - mean * mean;
    float sc = rsqrtf(var + BN_EPS) * g[c];
    float sh = bb[c] - mean * sc;
    int py2 = q2 / 7, px2 = q2 - py2 * 7;
    int q = (py2 * 2) * 14 + px2 * 2;
    const float* p = Pt + ((size_t)b * 196 + q) * 64 + c;
    float v0 = fmaxf(p[0] * sc + sh, 0.f);
    float v1 = fmaxf(p[64] * sc + sh, 0.f);
    float v2 = fmaxf(p[14 * 64] * sc + sh, 0.f);
    float v3 = fmaxf(p[15 * 64] * sc + sh, 0.f);
    out[t] = fmaxf(fmaxf(v0, v1), fmaxf(v2, v3));
}

// ---------- transpose fc1_w into wT[(q2*64 + c)*64 + o] ----------

__global__ __launch_bounds__(256) void transpose_kernel(
        const float* __restrict__ w, float* __restrict__ wT) {
    int t = blockIdx.x * 256 + threadIdx.x;
    if (t >= 64 * 3136) return;
    int o = t & 63;
    int m = t >> 6;
    int c = m & 63;
    int q2 = m >> 6;
    wT[(size_t)m * 64 + o] = w[(size_t)o * 3136 + c * 49 + q2];
}

// ---------- fc1: pooled2 flat [1024,3136] @ wT -> z [1024,64] ----------

__global__ __launch_bounds__(256) void fc1_kernel(
        const float* __restrict__ xin, const float* __restrict__ wT,
        const float* __restrict__ bias, float* __restrict__ z) {
    __shared__ float xs[4 * 3136];
    __shared__ float red[4][4][64];
    int b0 = blockIdx.x * 4;
    for (int j = threadIdx.x; j < 4 * 3136; j += 256)
        xs[j] = xin[(size_t)b0 * 3136 + j];
    __syncthreads();
    int o = threadIdx.x & 63, q = threadIdx.x >> 6;
    float s0 = 0.f, s1 = 0.f, s2 = 0.f, s3 = 0.f;
    for (int j = q * 784; j < q * 784 + 784; ++j) {
        float wv = wT[(size_t)j * 64 + o];
        s0 += xs[j] * wv;
        s1 += xs[3136 + j] * wv;
        s2 += xs[2 * 3136 + j] * wv;
        s3 += xs[3 * 3136 + j] * wv;
    }
    red[0][q][o] = s0; red[1][q][o] = s1; red[2][q][o] = s2; red[3][q][o] = s3;
    __syncthreads();
    int bb = threadIdx.x >> 6;
    float tot = red[bb][0][o] + red[bb][1][o] + red[bb][2][o] + red[bb][3][o] + bias[o];
    z[((size_t)(b0 + bb)) * 64 + o] = tot;
}

// ---------- bn1d column stats over z [1024,64] ----------

__global__ __launch_bounds__(256) void colstats_kernel(
        const float* __restrict__ z, float* __restrict__ stats) {
    int c = blockIdx.x;
    float s = 0.f, s2 = 0.f;
    for (int b = threadIdx.x; b < 1024; b += 256) {
        float v = z[(size_t)b * 64 + c];
        s += v; s2 += v * v;
    }
#pragma unroll
    for (int off = 32; off > 0; off >>= 1) {
        s  += __shfl_down(s, off, 64);
        s2 += __shfl_down(s2, off, 64);
    }
    __shared__ float ls[8];
    int w = threadIdx.x >> 6;
    if ((threadIdx.x & 63) == 0) { ls[w * 2] = s; ls[w * 2 + 1] = s2; }
    __syncthreads();
    if (threadIdx.x == 0) {
        stats[2 * c]     = ls[0] + ls[2] + ls[4] + ls[6];
        stats[2 * c + 1] = ls[1] + ls[3] + ls[5] + ls[7];
    }
}

// ---------- final: bn1d + relu + fc2 -> out [1024,10] ----------

__global__ __launch_bounds__(256) void final_kernel(
        const float* __restrict__ z, const float* __restrict__ stats,
        const float* __restrict__ g, const float* __restrict__ bb,
        const float* __restrict__ w2, const float* __restrict__ b2,
        float* __restrict__ out) {
    int t = blockIdx.x * 256 + threadIdx.x;
    if (t >= 10240) return;
    int o = t % 10, b = t / 10;
    float acc = b2[o];
#pragma unroll 8
    for (int c = 0; c < 64; ++c) {
        float mean = stats[2 * c] * (1.0f / 1024.0f);
        float var  = stats[2 * c + 1] * (1.0f / 1024.0f) - mean * mean;
        float sc = rsqrtf(var + BN_EPS) * g[c];
        float a = fmaxf(z[(size_t)b * 64 + c] * sc + (bb[c] - mean * sc), 0.f);
        acc += a * w2[o * 64 + c];
    }
    out[t] = acc;
}

// ---------- launch ----------

extern "C" void kernel_launch(void* const* d_in, const int* in_sizes, int n_in,
                              void* d_out, int out_size, void* d_ws, size_t ws_size,
                              hipStream_t stream) {
    const float* x   = (const float*)d_in[0];
    const float* bw1 = (const float*)d_in[1];
    const float* sw1 = (const float*)d_in[2];
    const float* g1  = (const float*)d_in[3];
    const float* b1  = (const float*)d_in[4];
    const float* bw2 = (const float*)d_in[5];
    const float* sw2 = (const float*)d_in[6];
    const float* g2  = (const float*)d_in[7];
    const float* b2v = (const float*)d_in[8];
    const float* fw1 = (const float*)d_in[9];
    const float* fb1 = (const float*)d_in[10];
    const float* g3  = (const float*)d_in[11];
    const float* b3  = (const float*)d_in[12];
    const float* fw2 = (const float*)d_in[13];
    const float* fb2 = (const float*)d_in[14];
    float* out = (float*)d_out;

    char* ws = (char*)d_ws;
    // region A [0, 58 MB): part1 (3.94 MB) during conv1 (dead after redstats1),
    //   then Pt [200704][64] (51.38 MB) + part2 at +51,380,224 (6.4 MB)
    float* part1  = (float*)(ws);
    float* Pt     = (float*)(ws);
    float* part2  = (float*)(ws + 51380224);
    // Wf (80 KB) + Wf1 (4 KB) in the dead gap between region A and region B
    _Float16* Wf  = (_Float16*)(ws + 100000000);
    _Float16* Wf1 = (_Float16*)(ws + 100131072);
    // region B: pooled raw [1024][225][32] (29.5 MB); later pooled2 [1024,3136]
    float* pooled = (float*)(ws + 125960192);
    float* z      = (float*)(ws + 155451392);   // [1024,64]
    float* wT     = (float*)(ws + 155713536);   // [3136,64]
    float* stats1 = (float*)(ws + 156516352);   // 64 floats
    float* stats2 = (float*)(ws + 156516608);   // 128 floats
    float* stats3 = (float*)(ws + 156517120);   // 128 floats

    transpose_kernel<<<(64 * 3136 + 255) / 256, 256, 0, stream>>>(fw1, wT);
    wconv16_kernel<<<160, 256, 0, stream>>>(bw2, sw2, Wf);
    wconv1h_kernel<<<8, 256, 0, stream>>>(bw1, sw1, Wf1);

    conv1_kernel<<<15376, 256, 0, stream>>>(x, Wf1, pooled, part1);
    redstats_kernel<<<64, 256, 0, stream>>>(part1, stats1, NSLOT1);

    conv2_kernel<<<3136, 256, 0, stream>>>(pooled, stats1, g1, b1,
                                           Wf, Pt, part2);
    redstats_kernel<<<128, 256, 0, stream>>>(part2, stats2, NSLOT2);

    float* pooled2 = pooled;  // region B reuse (pooled raw dead after conv2)
    bnpool2_kernel<<<(1024 * 49 * 64 + 255) / 256, 256, 0, stream>>>(
        Pt, stats2, g2, b2v, pooled2);

    fc1_kernel<<<256, 256, 0, stream>>>(pooled2, wT, fb1, z);
    colstats_kernel<<<64, 256, 0, stream>>>(z, stats3);
    final_kernel<<<(10240 + 255) / 256, 256, 0, stream>>>(z, stats3, g3, b3, fw2, fb2, out);
}

// Round 4
// 338.238 us; speedup vs baseline: 1.4360x; 1.0435x over previous
//
#include <hip/hip_runtime.h>
#include <math.h>

#define BN_EPS 1e-5f
#define NSLOT1 15376  // conv1: one slot per block (14400 interior + 976 border)
#define NSLOT2 3136   // conv2: one slot per block

typedef __attribute__((ext_vector_type(8))) _Float16 f16x8;
typedef __attribute__((ext_vector_type(2))) __fp16 fp16v2;
typedef __attribute__((ext_vector_type(4))) float f32x4;

// ---------- helpers ----------

__device__ __forceinline__ float siluf(float v) {
    // fast rcp instead of precise divide (~1 ulp, fine vs fp16 downstream)
    return v * __builtin_amdgcn_rcpf(1.0f + __expf(-v));
}

// 6*basis_i(x), i=0..3, cubic B-spline on knots g[j]=2j-7.
// 6*B(t) = max(0,2-|t|)^3 - 4*max(0,1-|t|)^3 with t = u-(i+2), u=(x+7)/2.
// The 1/6 is folded into the spline weights at prep time. Branchless,
// no int convert, 4 independent FMA-pipe chains.
__device__ __forceinline__ void expand5(float v, float f[5]) {
    f[0] = siluf(v);
    float u = (v + 7.0f) * 0.5f;
#pragma unroll
    for (int i = 0; i < 4; ++i) {
        float a = fabsf(u - (float)(i + 2));
        float p = fmaxf(2.0f - a, 0.0f);
        float q = fmaxf(1.0f - a, 0.0f);
        f[i + 1] = p * p * p - 4.0f * (q * q * q);
    }
}

__device__ __forceinline__ int pkh(float a, float b) {
    union { fp16v2 h2; int i; } u;
    u.h2 = __builtin_amdgcn_cvt_pkrtz(a, b);
    return u.i;
}

// ---------- pre-convert conv1 weights to f16 (spline weights scaled 1/6) ----------
// K layout: k = g*16 + ql*5 + f for value i = g*3+ql (i = c*4+dy*2+dx), f=0..4

__global__ __launch_bounds__(256) void wconv1h_kernel(
        const float* __restrict__ bw, const float* __restrict__ sw,
        _Float16* __restrict__ Wf1) {
    int t = blockIdx.x * 256 + threadIdx.x;
    if (t >= 32 * 64) return;
    int n = t >> 6;
    int k = t & 63;
    int g = k >> 4, loc = k & 15;
    float val = 0.f;
    if (loc < 15) {
        int ql = loc / 5, f = loc - ql * 5;
        int i = g * 3 + ql;
        val = (f == 0) ? bw[n * 12 + i]
                       : sw[(n * 12 + i) * 4 + f - 1] * (1.0f / 6.0f);
    }
    Wf1[t] = (_Float16)val;
}

// ---------- conv1 as fp16 MFMA GEMM + fused raw maxpool + stats ----------

#define E_LDW 74  // 64 halves data + 10 pad (148B stride: odd dword step)

__global__ __launch_bounds__(256, 8) void conv1_kernel(
        const float* __restrict__ x, const _Float16* __restrict__ Wf1,
        float* __restrict__ pooled, float* __restrict__ part) {
    __shared__ _Float16 Eh[64 * E_LDW];
    __shared__ float Rs[4][64];

    int t = threadIdx.x;
    int lane = t & 63, wv = t >> 6;
    int rl = lane & 15, vg = lane >> 4;
    int l15 = rl, quad = vg;

    bool interior = blockIdx.x < 14400;
    int b, py, px;
    if (interior) {
        int mrow = blockIdx.x * 64 + wv * 16 + rl;
        int g4 = mrow >> 2, pp = mrow & 3;
        b = g4 / 225;
        int cell = g4 - b * 225;
        int pm = cell / 15, pn = cell - pm * 15;
        py = 2 * pm + (pp >> 1);
        px = 2 * pn + (pp & 1);
    } else {
        int j = (blockIdx.x - 14400) * 64 + wv * 16 + rl;
        b = j / 61;
        int r = j - b * 61;
        py = (r < 31) ? 30 : (r - 31);
        px = (r < 31) ? r : 30;
    }

    // ---- expand this lane's 3 window values -> 15 fp16 + zero pad ----
    float fv[16];
    fv[15] = 0.f;
#pragma unroll
    for (int q = 0; q < 3; ++q) {
        int i = vg * 3 + q;
        int c = i >> 2, dy = (i >> 1) & 1, dx = i & 1;
        float v = x[((size_t)(b * 3 + c)) * 1024 + (py + dy) * 32 + (px + dx)];
        expand5(v, &fv[q * 5]);
    }
    int* dst = (int*)&Eh[(wv * 16 + rl) * E_LDW + vg * 16];
#pragma unroll
    for (int k2 = 0; k2 < 8; ++k2) dst[k2] = pkh(fv[2 * k2], fv[2 * k2 + 1]);

    // ---- MFMA: 16 patches x 32 outputs, K=64 (no barrier: same-wave LDS) ----
    f32x4 acc[2];
    acc[0] = (f32x4){0.f, 0.f, 0.f, 0.f};
    acc[1] = (f32x4){0.f, 0.f, 0.f, 0.f};
    const _Float16* Ew = &Eh[(wv * 16 + l15) * E_LDW + quad * 8];
#pragma unroll
    for (int ks = 0; ks < 2; ++ks) {
        f16x8 a = *(const f16x8*)(Ew + ks * 32);
#pragma unroll
        for (int nt = 0; nt < 2; ++nt) {
            f16x8 bf = *(const f16x8*)&Wf1[(size_t)(nt * 16 + l15) * 64
                                           + ks * 32 + quad * 8];
            acc[nt] = __builtin_amdgcn_mfma_f32_16x16x32_f16(a, bf, acc[nt], 0, 0, 0);
        }
    }

    // ---- pooled write (interior): lane's 4 regs = one pool window ----
    if (interior) {
        int g4 = blockIdx.x * 16 + wv * 4 + quad;
        float* dp = pooled + (size_t)g4 * 32 + l15;
        dp[0]  = fmaxf(fmaxf(acc[0][0], acc[0][1]), fmaxf(acc[0][2], acc[0][3]));
        dp[16] = fmaxf(fmaxf(acc[1][0], acc[1][1]), fmaxf(acc[1][2], acc[1][3]));
    }

    // ---- stats: per-lane 4-row sums, reduce across quads, then waves ----
    float s0 = acc[0][0] + acc[0][1] + acc[0][2] + acc[0][3];
    float q0 = acc[0][0] * acc[0][0] + acc[0][1] * acc[0][1]
             + acc[0][2] * acc[0][2] + acc[0][3] * acc[0][3];
    float s1 = acc[1][0] + acc[1][1] + acc[1][2] + acc[1][3];
    float q1 = acc[1][0] * acc[1][0] + acc[1][1] * acc[1][1]
             + acc[1][2] * acc[1][2] + acc[1][3] * acc[1][3];
    s0 += __shfl_down(s0, 32, 64); s0 += __shfl_down(s0, 16, 64);
    q0 += __shfl_down(q0, 32, 64); q0 += __shfl_down(q0, 16, 64);
    s1 += __shfl_down(s1, 32, 64); s1 += __shfl_down(s1, 16, 64);
    q1 += __shfl_down(q1, 32, 64); q1 += __shfl_down(q1, 16, 64);
    if (lane < 16) {
        Rs[wv][2 * l15]          = s0;
        Rs[wv][2 * l15 + 1]      = q0;
        Rs[wv][32 + 2 * l15]     = s1;
        Rs[wv][32 + 2 * l15 + 1] = q1;
    }
    __syncthreads();
    if (t < 64)
        part[(size_t)t * NSLOT1 + blockIdx.x] =
            Rs[0][t] + Rs[1][t] + Rs[2][t] + Rs[3][t];
}

// ---------- pre-convert conv2 weights to f16 (spline weights scaled 1/6) ----------

__global__ __launch_bounds__(256) void wconv16_kernel(
        const float* __restrict__ bw, const float* __restrict__ sw,
        _Float16* __restrict__ Wf) {
    int t = blockIdx.x * 256 + threadIdx.x;
    if (t >= 64 * 640) return;
    int n = t / 640;
    int k = t - n * 640;
    int c = k / 20;
    int r = k - c * 20;
    int s = r / 5;
    int f = r - s * 5;
    float val = (f == 0) ? bw[n * 128 + c * 4 + s]
                         : sw[n * 512 + c * 16 + s * 4 + (f - 1)] * (1.0f / 6.0f);
    Wf[t] = (_Float16)val;
}

// ---------- conv2 helpers ----------

#define C2_LDW 170  // 160 halves data + 10 pad (340B stride: odd dword step)

__device__ __forceinline__ void c2_load(
        const float* __restrict__ pooled, const float* __restrict__ stats1,
        const float* __restrict__ g1v, const float* __restrict__ b1v,
        int c, const size_t pwoff[2], float pv[2][4], float pst[4]) {
    pst[0] = stats1[2 * c];
    pst[1] = stats1[2 * c + 1];
    pst[2] = g1v[c];
    pst[3] = b1v[c];
#pragma unroll
    for (int cc = 0; cc < 2; ++cc) {
        const float* pw = pooled + pwoff[cc] + c;
        pv[cc][0] = pw[0];
        pv[cc][1] = pw[32];
        pv[cc][2] = pw[480];
        pv[cc][3] = pw[512];
    }
}

__device__ __forceinline__ void c2_expand(
        const float pv[2][4], const float pst[4], int ew[2][10]) {
    const float invN1 = 1.0f / (1024.0f * 961.0f);
    float mean = pst[0] * invN1;
    float var  = pst[1] * invN1 - mean * mean;
    float sc = rsqrtf(var + BN_EPS) * pst[2];
    float sh = pst[3] - mean * sc;
#pragma unroll
    for (int cc = 0; cc < 2; ++cc) {
        float f[20];
#pragma unroll
        for (int s = 0; s < 4; ++s) {
            float v = fmaxf(pv[cc][s] * sc + sh, 0.f);
            expand5(v, &f[s * 5]);
        }
#pragma unroll
        for (int i = 0; i < 10; ++i) ew[cc][i] = pkh(f[2 * i], f[2 * i + 1]);
    }
}

__device__ __forceinline__ void c2_write(
        _Float16* Eh, const int m[2], int cl, const int ew[2][10]) {
#pragma unroll
    for (int cc = 0; cc < 2; ++cc) {
        int* dst = (int*)&Eh[m[cc] * C2_LDW + cl * 20];
#pragma unroll
        for (int i = 0; i < 10; ++i) dst[i] = ew[cc][i];
    }
}

// MFMA over all 64 patch rows with the wave's 16-output B-fragments in regs.
// ks outer / mt inner: 4 independent acc chains between dependent uses.
__device__ __forceinline__ void c2_mfma(
        const _Float16* Eh, const f16x8 bfr[5],
        int l15, int quad, f32x4 acc[4]) {
#pragma unroll
    for (int ks = 0; ks < 5; ++ks) {
        int ko = ks * 32 + quad * 8;
#pragma unroll
        for (int mt = 0; mt < 4; ++mt) {
            f16x8 a = *(const f16x8*)&Eh[(mt * 16 + l15) * C2_LDW + ko];
            acc[mt] = __builtin_amdgcn_mfma_f32_16x16x32_f16(a, bfr[ks], acc[mt], 0, 0, 0);
        }
    }
}

// ---------- conv2 (fp16 MFMA, N-split waves, B-fragments register-prefetched) ----------
// Wave wv owns cols [wv*16, wv*16+16) x all 64 patch rows: per-wave Wf traffic
// drops 4x (20 KB, 5 loads/group) and fits a 20-VGPR prefetch one group ahead.
// Per group: expand(g+1)[VALU] -> mfma(g)[LDS A x reg B] -> barrier ->
// prefetch B(g+1) -> ds_write(g+1) -> barrier. The B-load latency hides under
// write+barrier+expand of the next iteration.

__global__ __launch_bounds__(256, 6) void conv2_kernel(
        const float* __restrict__ pooled, const float* __restrict__ stats1,
        const float* __restrict__ g1v, const float* __restrict__ b1v,
        const _Float16* __restrict__ Wf, float* __restrict__ Pt,
        float* __restrict__ part) {
    __shared__ _Float16 Eh[64 * C2_LDW];
    __shared__ float Rs[4][32];

    int t = threadIdx.x;
    int lane = t & 63, wv = t >> 6;
    int quad = lane >> 4, l15 = lane & 15;

    int cl = lane & 7;           // channel within group (8 per group)
    int rl = lane >> 3;          // 0..7; rows rl and rl+8 of this wave's tile
    int m[2];
    size_t pwoff[2];
#pragma unroll
    for (int cc = 0; cc < 2; ++cc) {
        m[cc] = wv * 16 + rl + 8 * cc;
        int patch = blockIdx.x * 64 + m[cc];
        int pb = patch / 196;
        int q = patch - pb * 196;
        int py = q / 14;
        int px = q - py * 14;
        pwoff[cc] = ((size_t)pb * 225 + py * 15 + px) * 32;
    }

    const _Float16* Wb = Wf + (size_t)(wv * 16 + l15) * 640 + quad * 8;

    f32x4 acc[4];
#pragma unroll
    for (int mt = 0; mt < 4; ++mt) acc[mt] = (f32x4){0.f, 0.f, 0.f, 0.f};

    float pvA[2][4], pstA[4], pvB[2][4], pstB[4];
    int ew[2][10];
    f16x8 bfr[5];

    // prologue: B(g0) prefetch, pooled loads g0/g1, expand+write g0
#pragma unroll
    for (int ks = 0; ks < 5; ++ks) bfr[ks] = *(const f16x8*)(Wb + ks * 32);
    c2_load(pooled, stats1, g1v, b1v, cl, pwoff, pvA, pstA);
    c2_load(pooled, stats1, g1v, b1v, 8 + cl, pwoff, pvB, pstB);
    c2_expand(pvA, pstA, ew);
    c2_write(Eh, m, cl, ew);
    __syncthreads();

    // g = 0
    c2_load(pooled, stats1, g1v, b1v, 16 + cl, pwoff, pvA, pstA);
    c2_expand(pvB, pstB, ew);
    c2_mfma(Eh, bfr, l15, quad, acc);
    __syncthreads();
#pragma unroll
    for (int ks = 0; ks < 5; ++ks) bfr[ks] = *(const f16x8*)(Wb + 160 + ks * 32);
    c2_write(Eh, m, cl, ew);
    __syncthreads();

    // g = 1
    c2_load(pooled, stats1, g1v, b1v, 24 + cl, pwoff, pvB, pstB);
    c2_expand(pvA, pstA, ew);
    c2_mfma(Eh, bfr, l15, quad, acc);
    __syncthreads();
#pragma unroll
    for (int ks = 0; ks < 5; ++ks) bfr[ks] = *(const f16x8*)(Wb + 320 + ks * 32);
    c2_write(Eh, m, cl, ew);
    __syncthreads();

    // g = 2
    c2_expand(pvB, pstB, ew);
    c2_mfma(Eh, bfr, l15, quad, acc);
    __syncthreads();
#pragma unroll
    for (int ks = 0; ks < 5; ++ks) bfr[ks] = *(const f16x8*)(Wb + 480 + ks * 32);
    c2_write(Eh, m, cl, ew);
    __syncthreads();

    // g = 3
    c2_mfma(Eh, bfr, l15, quad, acc);

    // ---- store: rows blk*64 + mt*16 + quad*4 + reg, cols wv*16 + l15 ----
    int o = wv * 16 + l15;
#pragma unroll
    for (int mt = 0; mt < 4; ++mt) {
        int rowb = blockIdx.x * 64 + mt * 16 + quad * 4;
#pragma unroll
        for (int reg = 0; reg < 4; ++reg)
            Pt[(size_t)(rowb + reg) * 64 + o] = acc[mt][reg];
    }
    // ---- fused stats: this wave holds ALL 64 rows of its 16 cols ----
    float s = 0.f, s2 = 0.f;
#pragma unroll
    for (int mt = 0; mt < 4; ++mt)
#pragma unroll
        for (int reg = 0; reg < 4; ++reg) {
            float a = acc[mt][reg];
            s += a;
            s2 += a * a;
        }
    s  += __shfl_down(s, 16, 64);  s  += __shfl_down(s, 32, 64);
    s2 += __shfl_down(s2, 16, 64); s2 += __shfl_down(s2, 32, 64);
    if (lane < 16) {
        part[(size_t)(2 * o) * NSLOT2 + blockIdx.x]     = s;
        part[(size_t)(2 * o + 1) * NSLOT2 + blockIdx.x] = s2;
    }
    (void)Rs;
}

// ---------- reduce per-wave partials -> stats ----------

__global__ __launch_bounds__(256) void redstats_kernel(
        const float* __restrict__ part, float* __restrict__ stats, int nblk) {
    int p = blockIdx.x;
    const float* src = part + (size_t)p * nblk;
    float s = 0.f;
    for (int j = threadIdx.x; j < nblk; j += 256) s += src[j];
#pragma unroll
    for (int off = 32; off > 0; off >>= 1) s += __shfl_down(s, off, 64);
    __shared__ float ls[4];
    if ((threadIdx.x & 63) == 0) ls[threadIdx.x >> 6] = s;
    __syncthreads();
    if (threadIdx.x == 0) stats[p] = ls[0] + ls[1] + ls[2] + ls[3];
}

// ---------- stage-2 BN + ReLU + pool from Pt [patch][64] -> pooled2 [b][q2*64+c] ----------

__global__ __launch_bounds__(256) void bnpool2_kernel(
        const float* __restrict__ Pt, const float* __restrict__ stats,
        const float* __restrict__ g, const float* __restrict__ bb,
        float* __restrict__ out) {
    int t = blockIdx.x * 256 + threadIdx.x;
    if (t >= 1024 * 49 * 64) return;
    int c  = t & 63;
    int q2 = (t >> 6) % 49;
    int b  = t / (49 * 64);
    float mean = stats[2 * c] * (1.0f / 200704.0f);
    float var  = stats[2 * c + 1] * (1.0f / 200704.0f) - mean * mean;
    float sc = rsqrtf(var + BN_EPS) * g[c];
    float sh = bb[c] - mean * sc;
    int py2 = q2 / 7, px2 = q2 - py2 * 7;
    int q = (py2 * 2) * 14 + px2 * 2;
    const float* p = Pt + ((size_t)b * 196 + q) * 64 + c;
    float v0 = fmaxf(p[0] * sc + sh, 0.f);
    float v1 = fmaxf(p[64] * sc + sh, 0.f);
    float v2 = fmaxf(p[14 * 64] * sc + sh, 0.f);
    float v3 = fmaxf(p[15 * 64] * sc + sh, 0.f);
    out[t] = fmaxf(fmaxf(v0, v1), fmaxf(v2, v3));
}

// ---------- transpose fc1_w into wT[(q2*64 + c)*64 + o] ----------

__global__ __launch_bounds__(256) void transpose_kernel(
        const float* __restrict__ w, float* __restrict__ wT) {
    int t = blockIdx.x * 256 + threadIdx.x;
    if (t >= 64 * 3136) return;
    int o = t & 63;
    int m = t >> 6;
    int c = m & 63;
    int q2 = m >> 6;
    wT[(size_t)m * 64 + o] = w[(size_t)o * 3136 + c * 49 + q2];
}

// ---------- fc1: pooled2 flat [1024,3136] @ wT -> z [1024,64] ----------

__global__ __launch_bounds__(256) void fc1_kernel(
        const float* __restrict__ xin, const float* __restrict__ wT,
        const float* __restrict__ bias, float* __restrict__ z) {
    __shared__ float xs[4 * 3136];
    __shared__ float red[4][4][64];
    int b0 = blockIdx.x * 4;
    for (int j = threadIdx.x; j < 4 * 3136; j += 256)
        xs[j] = xin[(size_t)b0 * 3136 + j];
    __syncthreads();
    int o = threadIdx.x & 63, q = threadIdx.x >> 6;
    float s0 = 0.f, s1 = 0.f, s2 = 0.f, s3 = 0.f;
    for (int j = q * 784; j < q * 784 + 784; ++j) {
        float wv = wT[(size_t)j * 64 + o];
        s0 += xs[j] * wv;
        s1 += xs[3136 + j] * wv;
        s2 += xs[2 * 3136 + j] * wv;
        s3 += xs[3 * 3136 + j] * wv;
    }
    red[0][q][o] = s0; red[1][q][o] = s1; red[2][q][o] = s2; red[3][q][o] = s3;
    __syncthreads();
    int bb = threadIdx.x >> 6;
    float tot = red[bb][0][o] + red[bb][1][o] + red[bb][2][o] + red[bb][3][o] + bias[o];
    z[((size_t)(b0 + bb)) * 64 + o] = tot;
}

// ---------- bn1d column stats over z [1024,64] ----------

__global__ __launch_bounds__(256) void colstats_kernel(
        const float* __restrict__ z, float* __restrict__ stats) {
    int c = blockIdx.x;
    float s = 0.f, s2 = 0.f;
    for (int b = threadIdx.x; b < 1024; b += 256) {
        float v = z[(size_t)b * 64 + c];
        s += v; s2 += v * v;
    }
#pragma unroll
    for (int off = 32; off > 0; off >>= 1) {
        s  += __shfl_down(s, off, 64);
        s2 += __shfl_down(s2, off, 64);
    }
    __shared__ float ls[8];
    int w = threadIdx.x >> 6;
    if ((threadIdx.x & 63) == 0) { ls[w * 2] = s; ls[w * 2 + 1] = s2; }
    __syncthreads();
    if (threadIdx.x == 0) {
        stats[2 * c]     = ls[0] + ls[2] + ls[4] + ls[6];
        stats[2 * c + 1] = ls[1] + ls[3] + ls[5] + ls[7];
    }
}

// ---------- final: bn1d + relu + fc2 -> out [1024,10] ----------

__global__ __launch_bounds__(256) void final_kernel(
        const float* __restrict__ z, const float* __restrict__ stats,
        const float* __restrict__ g, const float* __restrict__ bb,
        const float* __restrict__ w2, const float* __restrict__ b2,
        float* __restrict__ out) {
    int t = blockIdx.x * 256 + threadIdx.x;
    if (t >= 10240) return;
    int o = t % 10, b = t / 10;
    float acc = b2[o];
#pragma unroll 8
    for (int c = 0; c < 64; ++c) {
        float mean = stats[2 * c] * (1.0f / 1024.0f);
        float var  = stats[2 * c + 1] * (1.0f / 1024.0f) - mean * mean;
        float sc = rsqrtf(var + BN_EPS) * g[c];
        float a = fmaxf(z[(size_t)b * 64 + c] * sc + (bb[c] - mean * sc), 0.f);
        acc += a * w2[o * 64 + c];
    }
    out[t] = acc;
}

// ---------- launch ----------

extern "C" void kernel_launch(void* const* d_in, const int* in_sizes, int n_in,
                              void* d_out, int out_size, void* d_ws, size_t ws_size,
                              hipStream_t stream) {
    const float* x   = (const float*)d_in[0];
    const float* bw1 = (const float*)d_in[1];
    const float* sw1 = (const float*)d_in[2];
    const float* g1  = (const float*)d_in[3];
    const float* b1  = (const float*)d_in[4];
    const float* bw2 = (const float*)d_in[5];
    const float* sw2 = (const float*)d_in[6];
    const float* g2  = (const float*)d_in[7];
    const float* b2v = (const float*)d_in[8];
    const float* fw1 = (const float*)d_in[9];
    const float* fb1 = (const float*)d_in[10];
    const float* g3  = (const float*)d_in[11];
    const float* b3  = (const float*)d_in[12];
    const float* fw2 = (const float*)d_in[13];
    const float* fb2 = (const float*)d_in[14];
    float* out = (float*)d_out;

    char* ws = (char*)d_ws;
    // region A [0, 58 MB): part1 (3.94 MB) during conv1 (dead after redstats1),
    //   then Pt [200704][64] (51.38 MB) + part2 at +51,380,224 (1.6 MB)
    float* part1  = (float*)(ws);
    float* Pt     = (float*)(ws);
    float* part2  = (float*)(ws + 51380224);
    // Wf (80 KB) + Wf1 (4 KB) in the dead gap between region A and region B
    _Float16* Wf  = (_Float16*)(ws + 100000000);
    _Float16* Wf1 = (_Float16*)(ws + 100131072);
    // region B: pooled raw [1024][225][32] (29.5 MB); later pooled2 [1024,3136]
    float* pooled = (float*)(ws + 125960192);
    float* z      = (float*)(ws + 155451392);   // [1024,64]
    float* wT     = (float*)(ws + 155713536);   // [3136,64]
    float* stats1 = (float*)(ws + 156516352);   // 64 floats
    float* stats2 = (float*)(ws + 156516608);   // 128 floats
    float* stats3 = (float*)(ws + 156517120);   // 128 floats

    transpose_kernel<<<(64 * 3136 + 255) / 256, 256, 0, stream>>>(fw1, wT);
    wconv16_kernel<<<160, 256, 0, stream>>>(bw2, sw2, Wf);
    wconv1h_kernel<<<8, 256, 0, stream>>>(bw1, sw1, Wf1);

    conv1_kernel<<<15376, 256, 0, stream>>>(x, Wf1, pooled, part1);
    redstats_kernel<<<64, 256, 0, stream>>>(part1, stats1, NSLOT1);

    conv2_kernel<<<3136, 256, 0, stream>>>(pooled, stats1, g1, b1,
                                           Wf, Pt, part2);
    redstats_kernel<<<128, 256, 0, stream>>>(part2, stats2, NSLOT2);

    float* pooled2 = pooled;  // region B reuse (pooled raw dead after conv2)
    bnpool2_kernel<<<(1024 * 49 * 64 + 255) / 256, 256, 0, stream>>>(
        Pt, stats2, g2, b2v, pooled2);

    fc1_kernel<<<256, 256, 0, stream>>>(pooled2, wT, fb1, z);
    colstats_kernel<<<64, 256, 0, stream>>>(z, stats3);
    final_kernel<<<(10240 + 255) / 256, 256, 0, stream>>>(z, stats3, g3, b3, fw2, fb2, out);
}

// Round 5
// 262.702 us; speedup vs baseline: 1.8489x; 1.2875x over previous
//
#include <hip/hip_runtime.h>
#include <math.h>

#define BN_EPS 1e-5f

typedef __attribute__((ext_vector_type(8))) _Float16 f16x8;
typedef __attribute__((ext_vector_type(2))) __fp16 fp16v2;
typedef __attribute__((ext_vector_type(4))) float f32x4;

// ---------- helpers ----------

__device__ __forceinline__ float siluf(float v) {
    return v * __builtin_amdgcn_rcpf(1.0f + __expf(-v));
}

// 6*basis_i(x), i=0..3, cubic B-spline on knots g[j]=2j-7.
// 6*B(t) = max(0,2-|t|)^3 - 4*max(0,1-|t|)^3 with t = u-(i+2), u=(x+7)/2.
// The 1/6 is folded into the spline weights at prep time.
__device__ __forceinline__ void expand5(float v, float f[5]) {
    f[0] = siluf(v);
    float u = (v + 7.0f) * 0.5f;
#pragma unroll
    for (int i = 0; i < 4; ++i) {
        float a = fabsf(u - (float)(i + 2));
        float p = fmaxf(2.0f - a, 0.0f);
        float q = fmaxf(1.0f - a, 0.0f);
        f[i + 1] = p * p * p - 4.0f * (q * q * q);
    }
}

__device__ __forceinline__ int pkh(float a, float b) {
    union { fp16v2 h2; int i; } u;
    u.h2 = __builtin_amdgcn_cvt_pkrtz(a, b);
    return u.i;
}

// ---------- pre-convert conv1 weights to f16 (spline weights scaled 1/6) ----------
// K layout: k = g*16 + ql*5 + f for value i = g*3+ql (i = c*4+dy*2+dx), f=0..4

__global__ __launch_bounds__(256) void wconv1h_kernel(
        const float* __restrict__ bw, const float* __restrict__ sw,
        _Float16* __restrict__ Wf1) {
    int t = blockIdx.x * 256 + threadIdx.x;
    if (t >= 32 * 64) return;
    int n = t >> 6;
    int k = t & 63;
    int g = k >> 4, loc = k & 15;
    float val = 0.f;
    if (loc < 15) {
        int ql = loc / 5, f = loc - ql * 5;
        int i = g * 3 + ql;
        val = (f == 0) ? bw[n * 12 + i]
                       : sw[(n * 12 + i) * 4 + f - 1] * (1.0f / 6.0f);
    }
    Wf1[t] = (_Float16)val;
}

// ---------- conv1 as fp16 MFMA GEMM + fused raw maxpool + stats ----------

#define E_LDW 74  // 64 halves data + 10 pad

__global__ __launch_bounds__(256, 8) void conv1_kernel(
        const float* __restrict__ x, const _Float16* __restrict__ Wf1,
        float* __restrict__ pooled, float* __restrict__ part) {
    __shared__ _Float16 Eh[64 * E_LDW];
    __shared__ float Rs[4][64];

    int t = threadIdx.x;
    int lane = t & 63, wv = t >> 6;
    int rl = lane & 15, vg = lane >> 4;
    int l15 = rl, quad = vg;

    bool interior = blockIdx.x < 14400;
    int b, py, px;
    if (interior) {
        int mrow = blockIdx.x * 64 + wv * 16 + rl;
        int g4 = mrow >> 2, pp = mrow & 3;
        b = g4 / 225;
        int cell = g4 - b * 225;
        int pm = cell / 15, pn = cell - pm * 15;
        py = 2 * pm + (pp >> 1);
        px = 2 * pn + (pp & 1);
    } else {
        int j = (blockIdx.x - 14400) * 64 + wv * 16 + rl;
        b = j / 61;
        int r = j - b * 61;
        py = (r < 31) ? 30 : (r - 31);
        px = (r < 31) ? r : 30;
    }

    float fv[16];
    fv[15] = 0.f;
#pragma unroll
    for (int q = 0; q < 3; ++q) {
        int i = vg * 3 + q;
        int c = i >> 2, dy = (i >> 1) & 1, dx = i & 1;
        float v = x[((size_t)(b * 3 + c)) * 1024 + (py + dy) * 32 + (px + dx)];
        expand5(v, &fv[q * 5]);
    }
    int* dst = (int*)&Eh[(wv * 16 + rl) * E_LDW + vg * 16];
#pragma unroll
    for (int k2 = 0; k2 < 8; ++k2) dst[k2] = pkh(fv[2 * k2], fv[2 * k2 + 1]);

    f32x4 acc[2];
    acc[0] = (f32x4){0.f, 0.f, 0.f, 0.f};
    acc[1] = (f32x4){0.f, 0.f, 0.f, 0.f};
    const _Float16* Ew = &Eh[(wv * 16 + l15) * E_LDW + quad * 8];
#pragma unroll
    for (int ks = 0; ks < 2; ++ks) {
        f16x8 a = *(const f16x8*)(Ew + ks * 32);
#pragma unroll
        for (int nt = 0; nt < 2; ++nt) {
            f16x8 bf = *(const f16x8*)&Wf1[(size_t)(nt * 16 + l15) * 64
                                           + ks * 32 + quad * 8];
            acc[nt] = __builtin_amdgcn_mfma_f32_16x16x32_f16(a, bf, acc[nt], 0, 0, 0);
        }
    }

    if (interior) {
        int g4 = blockIdx.x * 16 + wv * 4 + quad;
        float* dp = pooled + (size_t)g4 * 32 + l15;
        dp[0]  = fmaxf(fmaxf(acc[0][0], acc[0][1]), fmaxf(acc[0][2], acc[0][3]));
        dp[16] = fmaxf(fmaxf(acc[1][0], acc[1][1]), fmaxf(acc[1][2], acc[1][3]));
    }

    float s0 = acc[0][0] + acc[0][1] + acc[0][2] + acc[0][3];
    float q0 = acc[0][0] * acc[0][0] + acc[0][1] * acc[0][1]
             + acc[0][2] * acc[0][2] + acc[0][3] * acc[0][3];
    float s1 = acc[1][0] + acc[1][1] + acc[1][2] + acc[1][3];
    float q1 = acc[1][0] * acc[1][0] + acc[1][1] * acc[1][1]
             + acc[1][2] * acc[1][2] + acc[1][3] * acc[1][3];
    s0 += __shfl_down(s0, 32, 64); s0 += __shfl_down(s0, 16, 64);
    q0 += __shfl_down(q0, 32, 64); q0 += __shfl_down(q0, 16, 64);
    s1 += __shfl_down(s1, 32, 64); s1 += __shfl_down(s1, 16, 64);
    q1 += __shfl_down(q1, 32, 64); q1 += __shfl_down(q1, 16, 64);
    if (lane < 16) {
        Rs[wv][2 * l15]          = s0;
        Rs[wv][2 * l15 + 1]      = q0;
        Rs[wv][32 + 2 * l15]     = s1;
        Rs[wv][32 + 2 * l15 + 1] = q1;
    }
    __syncthreads();
    // slot-major: 64 contiguous floats per block (4 sectors, no write amp)
    if (t < 64)
        part[(size_t)blockIdx.x * 64 + t] =
            Rs[0][t] + Rs[1][t] + Rs[2][t] + Rs[3][t];
}

// ---------- pre-convert conv2 weights to f16, k = s*160 + f*32 + c ----------
// (matches the unique-pixel LDS table layout; spline weights scaled 1/6)

__global__ __launch_bounds__(256) void wconv16_kernel(
        const float* __restrict__ bw, const float* __restrict__ sw,
        _Float16* __restrict__ Wf) {
    int t = blockIdx.x * 256 + threadIdx.x;
    if (t >= 64 * 640) return;
    int n = t / 640;
    int k = t - n * 640;
    int s = k / 160;
    int r = k - s * 160;
    int f = r >> 5;
    int c = r & 31;
    float val = (f == 0) ? bw[n * 128 + c * 4 + s]
                         : sw[n * 512 + c * 16 + s * 4 + (f - 1)] * (1.0f / 6.0f);
    Wf[t] = (_Float16)val;
}

// ---------- conv2: unique-pixel expansion + barrier-free MFMA loop ----------
// Block = 7x7 patch tile of one image (4096 blocks = 1024 img x 4 quadrants).
// Phase 1: expand the tile's 8x8x32 UNIQUE pooled pixels once (3.5x less VALU
// than per-window) into Eu[pos][f*32+c] (fp16). One barrier.
// Phase 2: pure MFMA: A = ds_read_b128 from Eu via per-lane precomputed row
// bases (K relaid as k = s*160 + f*32 + c so fragments are contiguous);
// B register-double-buffered one group ahead; no barriers.
// M rows 49..63 are padding -> read the zero row, contribute exact 0 to stats.

#define EU_LDW 168  // halves; 336B row stride: bank-base period 8, <=3-way

__device__ __forceinline__ void c2_loadb(const _Float16* __restrict__ Wb,
                                         int g, f16x8 bf[5]) {
#pragma unroll
    for (int ks = 0; ks < 5; ++ks)
        bf[ks] = *(const f16x8*)(Wb + g * 160 + ks * 32);
}

__device__ __forceinline__ void c2_mfma(const _Float16* Eu,
                                        const int abase[4][4], int g,
                                        int quad, const f16x8 bf[5],
                                        f32x4 acc[4]) {
#pragma unroll
    for (int ks = 0; ks < 5; ++ks) {
        int jo = ks * 32 + quad * 8;
#pragma unroll
        for (int mt = 0; mt < 4; ++mt) {
            f16x8 a = *(const f16x8*)&Eu[abase[mt][g] + jo];
            acc[mt] = __builtin_amdgcn_mfma_f32_16x16x32_f16(a, bf[ks], acc[mt], 0, 0, 0);
        }
    }
}

__global__ __launch_bounds__(256, 4) void conv2_kernel(
        const float* __restrict__ pooled, const float* __restrict__ stats1,
        const float* __restrict__ g1v, const float* __restrict__ b1v,
        const _Float16* __restrict__ Wf, float* __restrict__ Pt,
        float* __restrict__ part) {
    __shared__ _Float16 Eu[65 * EU_LDW];

    int t = threadIdx.x;
    int lane = t & 63, wv = t >> 6;
    int quad = lane >> 4, l15 = lane & 15;

    int blk = blockIdx.x;
    int b = blk >> 2;
    int py0 = ((blk >> 1) & 1) * 7;
    int px0 = (blk & 1) * 7;

    // issue this wave's B(g0) loads before the expand phase (latency overlap)
    const _Float16* Wb = Wf + (size_t)(wv * 16 + l15) * 640 + quad * 8;
    f16x8 bfA[5], bfB[5];
    c2_loadb(Wb, 0, bfA);

    // ---- phase 1: expand 8x8x32 unique pixels, 8 per thread ----
    {
        int c = t & 31;
        int yr = t >> 5;  // 0..7
        const float invN1 = 1.0f / (1024.0f * 961.0f);
        float mean = stats1[2 * c] * invN1;
        float var  = stats1[2 * c + 1] * invN1 - mean * mean;
        float sc = rsqrtf(var + BN_EPS) * g1v[c];
        float sh = b1v[c] - mean * sc;
        const float* prow = pooled + ((size_t)b * 225 + (py0 + yr) * 15 + px0) * 32 + c;
#pragma unroll
        for (int xx = 0; xx < 8; ++xx) {
            float v = fmaxf(prow[xx * 32] * sc + sh, 0.f);
            float f[5];
            expand5(v, f);
            _Float16* eb = &Eu[(yr * 8 + xx) * EU_LDW + c];
            eb[0]   = (_Float16)f[0];
            eb[32]  = (_Float16)f[1];
            eb[64]  = (_Float16)f[2];
            eb[96]  = (_Float16)f[3];
            eb[128] = (_Float16)f[4];
        }
    }
    // zero row (pos 64) for padding lanes
    if (t < 84) *(int*)((char*)&Eu[64 * EU_LDW] + t * 4) = 0;

    // per-lane A row bases: [mt][s], in halves
    int abase[4][4];
#pragma unroll
    for (int mt = 0; mt < 4; ++mt) {
        int m = mt * 16 + l15;
        if (m < 49) {
            int pr = m / 7, pc = m - pr * 7;
#pragma unroll
            for (int s = 0; s < 4; ++s)
                abase[mt][s] = ((pr + (s >> 1)) * 8 + pc + (s & 1)) * EU_LDW;
        } else {
#pragma unroll
            for (int s = 0; s < 4; ++s) abase[mt][s] = 64 * EU_LDW;
        }
    }
    __syncthreads();

    // ---- phase 2: barrier-free MFMA, B double-buffered one group ahead ----
    f32x4 acc[4];
#pragma unroll
    for (int mt = 0; mt < 4; ++mt) acc[mt] = (f32x4){0.f, 0.f, 0.f, 0.f};

    c2_loadb(Wb, 1, bfB);
    c2_mfma(Eu, abase, 0, quad, bfA, acc);
    c2_loadb(Wb, 2, bfA);
    c2_mfma(Eu, abase, 1, quad, bfB, acc);
    c2_loadb(Wb, 3, bfB);
    c2_mfma(Eu, abase, 2, quad, bfA, acc);
    c2_mfma(Eu, abase, 3, quad, bfB, acc);

    // ---- store: patch rows m = mt*16 + quad*4 + reg (m < 49), col o ----
    int o = wv * 16 + l15;
#pragma unroll
    for (int mt = 0; mt < 4; ++mt) {
#pragma unroll
        for (int reg = 0; reg < 4; ++reg) {
            int m = mt * 16 + quad * 4 + reg;
            if (m < 49) {
                int pr = m / 7, pc = m - pr * 7;
                int patch = (b * 14 + py0 + pr) * 14 + px0 + pc;
                Pt[(size_t)patch * 64 + o] = acc[mt][reg];
            }
        }
    }
    // ---- stats: wave holds all rows of its 16 cols (pads are exact 0) ----
    float s = 0.f, s2 = 0.f;
#pragma unroll
    for (int mt = 0; mt < 4; ++mt)
#pragma unroll
        for (int reg = 0; reg < 4; ++reg) {
            float a = acc[mt][reg];
            s += a;
            s2 += a * a;
        }
    s  += __shfl_down(s, 16, 64);  s  += __shfl_down(s, 32, 64);
    s2 += __shfl_down(s2, 16, 64); s2 += __shfl_down(s2, 32, 64);
    if (lane < 16) {
        part[(size_t)blk * 128 + 2 * o]     = s;
        part[(size_t)blk * 128 + 2 * o + 1] = s2;
    }
}

// ---------- reduce slot-major partials: stats[p] = sum_j part[j*stride+p] ----------

__global__ __launch_bounds__(256) void redstats_kernel(
        const float* __restrict__ part, float* __restrict__ stats,
        int nblk, int stride) {
    int p = blockIdx.x;
    float s = 0.f;
    for (int j = threadIdx.x; j < nblk; j += 256)
        s += part[(size_t)j * stride + p];
#pragma unroll
    for (int off = 32; off > 0; off >>= 1) s += __shfl_down(s, off, 64);
    __shared__ float ls[4];
    if ((threadIdx.x & 63) == 0) ls[threadIdx.x >> 6] = s;
    __syncthreads();
    if (threadIdx.x == 0) stats[p] = ls[0] + ls[1] + ls[2] + ls[3];
}

// ---------- stage-2 BN + ReLU + pool from Pt [patch][64] -> pooled2 ----------

__global__ __launch_bounds__(256) void bnpool2_kernel(
        const float* __restrict__ Pt, const float* __restrict__ stats,
        const float* __restrict__ g, const float* __restrict__ bb,
        float* __restrict__ out) {
    int t = blockIdx.x * 256 + threadIdx.x;
    if (t >= 1024 * 49 * 64) return;
    int c  = t & 63;
    int q2 = (t >> 6) % 49;
    int b  = t / (49 * 64);
    float mean = stats[2 * c] * (1.0f / 200704.0f);
    float var  = stats[2 * c + 1] * (1.0f / 200704.0f) - mean * mean;
    float sc = rsqrtf(var + BN_EPS) * g[c];
    float sh = bb[c] - mean * sc;
    int py2 = q2 / 7, px2 = q2 - py2 * 7;
    int q = (py2 * 2) * 14 + px2 * 2;
    const float* p = Pt + ((size_t)b * 196 + q) * 64 + c;
    float v0 = fmaxf(p[0] * sc + sh, 0.f);
    float v1 = fmaxf(p[64] * sc + sh, 0.f);
    float v2 = fmaxf(p[14 * 64] * sc + sh, 0.f);
    float v3 = fmaxf(p[15 * 64] * sc + sh, 0.f);
    out[t] = fmaxf(fmaxf(v0, v1), fmaxf(v2, v3));
}

// ---------- transpose fc1_w into wT[(q2*64 + c)*64 + o] ----------

__global__ __launch_bounds__(256) void transpose_kernel(
        const float* __restrict__ w, float* __restrict__ wT) {
    int t = blockIdx.x * 256 + threadIdx.x;
    if (t >= 64 * 3136) return;
    int o = t & 63;
    int m = t >> 6;
    int c = m & 63;
    int q2 = m >> 6;
    wT[(size_t)m * 64 + o] = w[(size_t)o * 3136 + c * 49 + q2];
}

// ---------- fc1: pooled2 flat [1024,3136] @ wT -> z [1024,64] ----------

__global__ __launch_bounds__(256) void fc1_kernel(
        const float* __restrict__ xin, const float* __restrict__ wT,
        const float* __restrict__ bias, float* __restrict__ z) {
    __shared__ float xs[4 * 3136];
    __shared__ float red[4][4][64];
    int b0 = blockIdx.x * 4;
    for (int j = threadIdx.x; j < 4 * 3136; j += 256)
        xs[j] = xin[(size_t)b0 * 3136 + j];
    __syncthreads();
    int o = threadIdx.x & 63, q = threadIdx.x >> 6;
    float s0 = 0.f, s1 = 0.f, s2 = 0.f, s3 = 0.f;
    for (int j = q * 784; j < q * 784 + 784; ++j) {
        float wv = wT[(size_t)j * 64 + o];
        s0 += xs[j] * wv;
        s1 += xs[3136 + j] * wv;
        s2 += xs[2 * 3136 + j] * wv;
        s3 += xs[3 * 3136 + j] * wv;
    }
    red[0][q][o] = s0; red[1][q][o] = s1; red[2][q][o] = s2; red[3][q][o] = s3;
    __syncthreads();
    int bb = threadIdx.x >> 6;
    float tot = red[bb][0][o] + red[bb][1][o] + red[bb][2][o] + red[bb][3][o] + bias[o];
    z[((size_t)(b0 + bb)) * 64 + o] = tot;
}

// ---------- bn1d column stats over z [1024,64] ----------

__global__ __launch_bounds__(256) void colstats_kernel(
        const float* __restrict__ z, float* __restrict__ stats) {
    int c = blockIdx.x;
    float s = 0.f, s2 = 0.f;
    for (int b = threadIdx.x; b < 1024; b += 256) {
        float v = z[(size_t)b * 64 + c];
        s += v; s2 += v * v;
    }
#pragma unroll
    for (int off = 32; off > 0; off >>= 1) {
        s  += __shfl_down(s, off, 64);
        s2 += __shfl_down(s2, off, 64);
    }
    __shared__ float ls[8];
    int w = threadIdx.x >> 6;
    if ((threadIdx.x & 63) == 0) { ls[w * 2] = s; ls[w * 2 + 1] = s2; }
    __syncthreads();
    if (threadIdx.x == 0) {
        stats[2 * c]     = ls[0] + ls[2] + ls[4] + ls[6];
        stats[2 * c + 1] = ls[1] + ls[3] + ls[5] + ls[7];
    }
}

// ---------- final: bn1d + relu + fc2 -> out [1024,10] ----------

__global__ __launch_bounds__(256) void final_kernel(
        const float* __restrict__ z, const float* __restrict__ stats,
        const float* __restrict__ g, const float* __restrict__ bb,
        const float* __restrict__ w2, const float* __restrict__ b2,
        float* __restrict__ out) {
    int t = blockIdx.x * 256 + threadIdx.x;
    if (t >= 10240) return;
    int o = t % 10, b = t / 10;
    float acc = b2[o];
#pragma unroll 8
    for (int c = 0; c < 64; ++c) {
        float mean = stats[2 * c] * (1.0f / 1024.0f);
        float var  = stats[2 * c + 1] * (1.0f / 1024.0f) - mean * mean;
        float sc = rsqrtf(var + BN_EPS) * g[c];
        float a = fmaxf(z[(size_t)b * 64 + c] * sc + (bb[c] - mean * sc), 0.f);
        acc += a * w2[o * 64 + c];
    }
    out[t] = acc;
}

// ---------- launch ----------

extern "C" void kernel_launch(void* const* d_in, const int* in_sizes, int n_in,
                              void* d_out, int out_size, void* d_ws, size_t ws_size,
                              hipStream_t stream) {
    const float* x   = (const float*)d_in[0];
    const float* bw1 = (const float*)d_in[1];
    const float* sw1 = (const float*)d_in[2];
    const float* g1  = (const float*)d_in[3];
    const float* b1  = (const float*)d_in[4];
    const float* bw2 = (const float*)d_in[5];
    const float* sw2 = (const float*)d_in[6];
    const float* g2  = (const float*)d_in[7];
    const float* b2v = (const float*)d_in[8];
    const float* fw1 = (const float*)d_in[9];
    const float* fb1 = (const float*)d_in[10];
    const float* g3  = (const float*)d_in[11];
    const float* b3  = (const float*)d_in[12];
    const float* fw2 = (const float*)d_in[13];
    const float* fb2 = (const float*)d_in[14];
    float* out = (float*)d_out;

    char* ws = (char*)d_ws;
    // region A [0, 58 MB): part1 [15376][64] (3.94 MB, dead after redstats1),
    //   then Pt [200704][64] (51.38 MB) + part2 [4096][128] at +51,380,224 (2 MB)
    float* part1  = (float*)(ws);
    float* Pt     = (float*)(ws);
    float* part2  = (float*)(ws + 51380224);
    // Wf (80 KB) + Wf1 (4 KB) in the dead gap between region A and region B
    _Float16* Wf  = (_Float16*)(ws + 100000000);
    _Float16* Wf1 = (_Float16*)(ws + 100131072);
    // region B: pooled raw [1024][225][32] (29.5 MB); later pooled2 [1024,3136]
    float* pooled = (float*)(ws + 125960192);
    float* z      = (float*)(ws + 155451392);   // [1024,64]
    float* wT     = (float*)(ws + 155713536);   // [3136,64]
    float* stats1 = (float*)(ws + 156516352);   // 64 floats
    float* stats2 = (float*)(ws + 156516608);   // 128 floats
    float* stats3 = (float*)(ws + 156517120);   // 128 floats

    transpose_kernel<<<(64 * 3136 + 255) / 256, 256, 0, stream>>>(fw1, wT);
    wconv16_kernel<<<160, 256, 0, stream>>>(bw2, sw2, Wf);
    wconv1h_kernel<<<8, 256, 0, stream>>>(bw1, sw1, Wf1);

    conv1_kernel<<<15376, 256, 0, stream>>>(x, Wf1, pooled, part1);
    redstats_kernel<<<64, 256, 0, stream>>>(part1, stats1, 15376, 64);

    conv2_kernel<<<4096, 256, 0, stream>>>(pooled, stats1, g1, b1,
                                           Wf, Pt, part2);
    redstats_kernel<<<128, 256, 0, stream>>>(part2, stats2, 4096, 128);

    float* pooled2 = pooled;  // region B reuse (pooled raw dead after conv2)
    bnpool2_kernel<<<(1024 * 49 * 64 + 255) / 256, 256, 0, stream>>>(
        Pt, stats2, g2, b2v, pooled2);

    fc1_kernel<<<256, 256, 0, stream>>>(pooled2, wT, fb1, z);
    colstats_kernel<<<64, 256, 0, stream>>>(z, stats3);
    final_kernel<<<(10240 + 255) / 256, 256, 0, stream>>>(z, stats3, g3, b3, fw2, fb2, out);
}

// Round 6
// 235.028 us; speedup vs baseline: 2.0666x; 1.1177x over previous
//
#include <hip/hip_runtime.h>
#include <math.h>

#define BN_EPS 1e-5f

typedef __attribute__((ext_vector_type(8))) _Float16 f16x8;
typedef __attribute__((ext_vector_type(4))) _Float16 f16x4;
typedef __attribute__((ext_vector_type(2))) __fp16 fp16v2;
typedef __attribute__((ext_vector_type(4))) float f32x4;

// ---------- helpers ----------

__device__ __forceinline__ float siluf(float v) {
    return v * __builtin_amdgcn_rcpf(1.0f + __expf(-v));
}

// 6*basis_i(x), i=0..3, cubic B-spline on knots g[j]=2j-7.
// 6*B(t) = max(0,2-|t|)^3 - 4*max(0,1-|t|)^3 with t = u-(i+2), u=(x+7)/2.
// The 1/6 is folded into the spline weights at prep time.
__device__ __forceinline__ void expand5(float v, float f[5]) {
    f[0] = siluf(v);
    float u = (v + 7.0f) * 0.5f;
#pragma unroll
    for (int i = 0; i < 4; ++i) {
        float a = fabsf(u - (float)(i + 2));
        float p = fmaxf(2.0f - a, 0.0f);
        float q = fmaxf(1.0f - a, 0.0f);
        f[i + 1] = p * p * p - 4.0f * (q * q * q);
    }
}

__device__ __forceinline__ int pkh(float a, float b) {
    union { fp16v2 h2; int i; } u;
    u.h2 = __builtin_amdgcn_cvt_pkrtz(a, b);
    return u.i;
}

// ---------- conv1 weights: Wf1[n][k], k = s*16 + f*3 + c (pad j=15 zero) ----------

__global__ __launch_bounds__(256) void wconv1h_kernel(
        const float* __restrict__ bw, const float* __restrict__ sw,
        _Float16* __restrict__ Wf1) {
    int t = blockIdx.x * 256 + threadIdx.x;
    if (t >= 32 * 64) return;
    int n = t >> 6;
    int k = t & 63;
    int s = k >> 4, j = k & 15;
    float val = 0.f;
    if (j < 15) {
        int f = j / 3, c = j - f * 3;
        int i = c * 4 + s;
        val = (f == 0) ? bw[n * 12 + i]
                       : sw[(n * 12 + i) * 4 + f - 1] * (1.0f / 6.0f);
    }
    Wf1[t] = (_Float16)val;
}

// ---------- conv1: unique-pixel expand + MFMA + fused pool + stats ----------
// Block = 8x8 window tile (ty,tx of 4x4) of one image; 16384 blocks.
// Phase 1: expand 9x9x3 UNIQUE pixels (1/thread) into Eu[pos][f*3+c] (fp16),
// 24-half row stride (48B, 16B-aligned). Windows y/x==31 invalid -> zero row
// (exact 0 contribution to stats). Phase 2: 2 ds_read_b128 + 4 MFMA per lane.
// Pool: lane's 4 acc regs = 4 windows in one row; horiz max in-lane, vert max
// via shfl_down(32); write fp16 pooled. Stats denominator stays 1024*961.

#define C1_LDW 24

__global__ __launch_bounds__(256, 8) void conv1_kernel(
        const float* __restrict__ x, const _Float16* __restrict__ Wf1,
        _Float16* __restrict__ pooled, float* __restrict__ part) {
    __shared__ _Float16 Eu[82 * C1_LDW];
    __shared__ float Rs[4][64];

    int t = threadIdx.x;
    int lane = t & 63, wv = t >> 6;
    int quad = lane >> 4, l15 = lane & 15;

    int blk = blockIdx.x;
    int b = blk >> 4;
    int ty = (blk >> 2) & 3, tx = blk & 3;

    // B prefetch: n = nt*16+l15, k = ks*32 + quad*8
    const _Float16* wb0 = Wf1 + (size_t)l15 * 64 + quad * 8;
    f16x8 bf00 = *(const f16x8*)(wb0);
    f16x8 bf01 = *(const f16x8*)(wb0 + 32);
    f16x8 bf10 = *(const f16x8*)(wb0 + 16 * 64);
    f16x8 bf11 = *(const f16x8*)(wb0 + 16 * 64 + 32);

    // ---- phase 1: 81 positions x 3 channels, one pixel per thread ----
    if (t < 243) {
        int c = t / 81;
        int pos = t - c * 81;
        int yy = pos / 9, xx = pos - yy * 9;
        int Y = ty * 8 + yy, X = tx * 8 + xx;
        float v = 0.f;
        if (Y < 32 && X < 32)
            v = x[((size_t)(b * 3 + c)) * 1024 + Y * 32 + X];
        float f[5];
        expand5(v, f);
        _Float16* eb = &Eu[pos * C1_LDW + c];
        eb[0]  = (_Float16)f[0];
        eb[3]  = (_Float16)f[1];
        eb[6]  = (_Float16)f[2];
        eb[9]  = (_Float16)f[3];
        eb[12] = (_Float16)f[4];
    }
    if (t < 24) Eu[81 * C1_LDW + t] = (_Float16)0.f;

    // per-lane A addresses: window m = wv*16 + l15 -> (wy,wx) in 8x8 grid
    int wy = 2 * wv + (l15 >> 3), wx = l15 & 7;
    bool valid = (ty * 8 + wy < 31) && (tx * 8 + wx < 31);
    int dxq = quad >> 1, hq = (quad & 1) * 8;
    int p0 = valid ? (wy * 9 + wx + dxq) * C1_LDW + hq : 81 * C1_LDW + hq;
    int p1 = valid ? ((wy + 1) * 9 + wx + dxq) * C1_LDW + hq : 81 * C1_LDW + hq;
    __syncthreads();

    f32x4 acc0 = (f32x4){0.f, 0.f, 0.f, 0.f};
    f32x4 acc1 = (f32x4){0.f, 0.f, 0.f, 0.f};
    f16x8 a0 = *(const f16x8*)&Eu[p0];
    acc0 = __builtin_amdgcn_mfma_f32_16x16x32_f16(a0, bf00, acc0, 0, 0, 0);
    acc1 = __builtin_amdgcn_mfma_f32_16x16x32_f16(a0, bf10, acc1, 0, 0, 0);
    f16x8 a1 = *(const f16x8*)&Eu[p1];
    acc0 = __builtin_amdgcn_mfma_f32_16x16x32_f16(a1, bf01, acc0, 0, 0, 0);
    acc1 = __builtin_amdgcn_mfma_f32_16x16x32_f16(a1, bf11, acc1, 0, 0, 0);

    // ---- pool: rows quad*4+reg; horiz pairs in-lane, vert via lane+32 ----
    float h00 = fmaxf(acc0[0], acc0[1]);
    float h01 = fmaxf(acc0[2], acc0[3]);
    float h10 = fmaxf(acc1[0], acc1[1]);
    float h11 = fmaxf(acc1[2], acc1[3]);
    float g00 = fmaxf(h00, __shfl_down(h00, 32, 64));
    float g01 = fmaxf(h01, __shfl_down(h01, 32, 64));
    float g10 = fmaxf(h10, __shfl_down(h10, 32, 64));
    float g11 = fmaxf(h11, __shfl_down(h11, 32, 64));
    if (lane < 32) {
        int pm = 4 * ty + wv;
        int pn0 = 4 * tx + (quad & 1) * 2;
        if (pm < 15) {
            size_t base = ((size_t)b * 225 + pm * 15) * 32;
            if (pn0 < 15) {
                pooled[base + pn0 * 32 + l15]      = (_Float16)g00;
                pooled[base + pn0 * 32 + 16 + l15] = (_Float16)g10;
            }
            if (pn0 + 1 < 15) {
                pooled[base + (pn0 + 1) * 32 + l15]      = (_Float16)g01;
                pooled[base + (pn0 + 1) * 32 + 16 + l15] = (_Float16)g11;
            }
        }
    }

    // ---- stats (invalid windows contribute exact 0) ----
    float s0 = acc0[0] + acc0[1] + acc0[2] + acc0[3];
    float q0 = acc0[0] * acc0[0] + acc0[1] * acc0[1]
             + acc0[2] * acc0[2] + acc0[3] * acc0[3];
    float s1 = acc1[0] + acc1[1] + acc1[2] + acc1[3];
    float q1 = acc1[0] * acc1[0] + acc1[1] * acc1[1]
             + acc1[2] * acc1[2] + acc1[3] * acc1[3];
    s0 += __shfl_down(s0, 32, 64); s0 += __shfl_down(s0, 16, 64);
    q0 += __shfl_down(q0, 32, 64); q0 += __shfl_down(q0, 16, 64);
    s1 += __shfl_down(s1, 32, 64); s1 += __shfl_down(s1, 16, 64);
    q1 += __shfl_down(q1, 32, 64); q1 += __shfl_down(q1, 16, 64);
    if (lane < 16) {
        Rs[wv][2 * l15]          = s0;
        Rs[wv][2 * l15 + 1]      = q0;
        Rs[wv][32 + 2 * l15]     = s1;
        Rs[wv][32 + 2 * l15 + 1] = q1;
    }
    __syncthreads();
    if (t < 64)
        part[(size_t)blk * 64 + t] = Rs[0][t] + Rs[1][t] + Rs[2][t] + Rs[3][t];
}

// ---------- conv2 weights fp16, k = s*160 + f*32 + c (spline scaled 1/6) ----------

__global__ __launch_bounds__(256) void wconv16_kernel(
        const float* __restrict__ bw, const float* __restrict__ sw,
        _Float16* __restrict__ Wf) {
    int t = blockIdx.x * 256 + threadIdx.x;
    if (t >= 64 * 640) return;
    int n = t / 640;
    int k = t - n * 640;
    int s = k / 160;
    int r = k - s * 160;
    int f = r >> 5;
    int c = r & 31;
    float val = (f == 0) ? bw[n * 128 + c * 4 + s]
                         : sw[n * 512 + c * 16 + s * 4 + (f - 1)] * (1.0f / 6.0f);
    Wf[t] = (_Float16)val;
}

// ---------- conv2: unique-pixel expansion + barrier-free MFMA ----------
// Phase-1 writes c-pair-packed dwords (2-way banks = free, was 4-way b16).

#define EU_LDW 168

__device__ __forceinline__ void c2_loadb(const _Float16* __restrict__ Wb,
                                         int g, f16x8 bf[5]) {
#pragma unroll
    for (int ks = 0; ks < 5; ++ks)
        bf[ks] = *(const f16x8*)(Wb + g * 160 + ks * 32);
}

__device__ __forceinline__ void c2_mfma(const _Float16* Eu,
                                        const int abase[4][4], int g,
                                        int quad, const f16x8 bf[5],
                                        f32x4 acc[4]) {
#pragma unroll
    for (int ks = 0; ks < 5; ++ks) {
        int jo = ks * 32 + quad * 8;
#pragma unroll
        for (int mt = 0; mt < 4; ++mt) {
            f16x8 a = *(const f16x8*)&Eu[abase[mt][g] + jo];
            acc[mt] = __builtin_amdgcn_mfma_f32_16x16x32_f16(a, bf[ks], acc[mt], 0, 0, 0);
        }
    }
}

__global__ __launch_bounds__(256, 6) void conv2_kernel(
        const _Float16* __restrict__ pooled, const float* __restrict__ stats1,
        const float* __restrict__ g1v, const float* __restrict__ b1v,
        const _Float16* __restrict__ Wf, _Float16* __restrict__ Pt,
        float* __restrict__ part) {
    __shared__ _Float16 Eu[65 * EU_LDW];

    int t = threadIdx.x;
    int lane = t & 63, wv = t >> 6;
    int quad = lane >> 4, l15 = lane & 15;

    int blk = blockIdx.x;
    int b = blk >> 2;
    int py0 = ((blk >> 1) & 1) * 7;
    int px0 = (blk & 1) * 7;

    const _Float16* Wb = Wf + (size_t)(wv * 16 + l15) * 640 + quad * 8;
    f16x8 bfA[5], bfB[5];
    c2_loadb(Wb, 0, bfA);

    // ---- phase 1: 8x8 pixels x 32 ch; thread = (c-pair, row, x-half) ----
    {
        int c2 = t & 15, c0 = c2 * 2;
        int yr = (t >> 4) & 7;
        int xh = t >> 7;
        const float invN1 = 1.0f / (1024.0f * 961.0f);
        float m0 = stats1[2 * c0] * invN1;
        float v0 = stats1[2 * c0 + 1] * invN1 - m0 * m0;
        float sc0 = rsqrtf(v0 + BN_EPS) * g1v[c0];
        float sh0 = b1v[c0] - m0 * sc0;
        float m1 = stats1[2 * c0 + 2] * invN1;
        float v1 = stats1[2 * c0 + 3] * invN1 - m1 * m1;
        float sc1 = rsqrtf(v1 + BN_EPS) * g1v[c0 + 1];
        float sh1 = b1v[c0 + 1] - m1 * sc1;
        const _Float16* prow =
            pooled + ((size_t)b * 225 + (py0 + yr) * 15 + px0) * 32 + c0;
#pragma unroll
        for (int xi = 0; xi < 4; ++xi) {
            int xx = xh * 4 + xi;
            fp16v2 v2 = *(const fp16v2*)(prow + xx * 32);
            float va = fmaxf((float)v2.x * sc0 + sh0, 0.f);
            float vb = fmaxf((float)v2.y * sc1 + sh1, 0.f);
            float fa[5], fb5[5];
            expand5(va, fa);
            expand5(vb, fb5);
            int* eb = (int*)&Eu[(yr * 8 + xx) * EU_LDW + c0];
            eb[0]  = pkh(fa[0], fb5[0]);
            eb[16] = pkh(fa[1], fb5[1]);
            eb[32] = pkh(fa[2], fb5[2]);
            eb[48] = pkh(fa[3], fb5[3]);
            eb[64] = pkh(fa[4], fb5[4]);
        }
    }
    if (t < 84) *(int*)((char*)&Eu[64 * EU_LDW] + t * 4) = 0;

    int abase[4][4];
#pragma unroll
    for (int mt = 0; mt < 4; ++mt) {
        int m = mt * 16 + l15;
        if (m < 49) {
            int pr = m / 7, pc = m - pr * 7;
#pragma unroll
            for (int s = 0; s < 4; ++s)
                abase[mt][s] = ((pr + (s >> 1)) * 8 + pc + (s & 1)) * EU_LDW;
        } else {
#pragma unroll
            for (int s = 0; s < 4; ++s) abase[mt][s] = 64 * EU_LDW;
        }
    }
    __syncthreads();

    f32x4 acc[4];
#pragma unroll
    for (int mt = 0; mt < 4; ++mt) acc[mt] = (f32x4){0.f, 0.f, 0.f, 0.f};

    c2_loadb(Wb, 1, bfB);
    c2_mfma(Eu, abase, 0, quad, bfA, acc);
    c2_loadb(Wb, 2, bfA);
    c2_mfma(Eu, abase, 1, quad, bfB, acc);
    c2_loadb(Wb, 3, bfB);
    c2_mfma(Eu, abase, 2, quad, bfA, acc);
    c2_mfma(Eu, abase, 3, quad, bfB, acc);

    // ---- store fp16 Pt ----
    int o = wv * 16 + l15;
#pragma unroll
    for (int mt = 0; mt < 4; ++mt) {
#pragma unroll
        for (int reg = 0; reg < 4; ++reg) {
            int m = mt * 16 + quad * 4 + reg;
            if (m < 49) {
                int pr = m / 7, pc = m - pr * 7;
                int patch = (b * 14 + py0 + pr) * 14 + px0 + pc;
                Pt[(size_t)patch * 64 + o] = (_Float16)acc[mt][reg];
            }
        }
    }
    float s = 0.f, s2 = 0.f;
#pragma unroll
    for (int mt = 0; mt < 4; ++mt)
#pragma unroll
        for (int reg = 0; reg < 4; ++reg) {
            float a = acc[mt][reg];
            s += a;
            s2 += a * a;
        }
    s  += __shfl_down(s, 16, 64);  s  += __shfl_down(s, 32, 64);
    s2 += __shfl_down(s2, 16, 64); s2 += __shfl_down(s2, 32, 64);
    if (lane < 16) {
        part[(size_t)blk * 128 + 2 * o]     = s;
        part[(size_t)blk * 128 + 2 * o + 1] = s2;
    }
}

// ---------- reduce slot-major partials ----------

__global__ __launch_bounds__(256) void redstats_kernel(
        const float* __restrict__ part, float* __restrict__ stats,
        int nblk, int stride) {
    int p = blockIdx.x;
    float s = 0.f;
    for (int j = threadIdx.x; j < nblk; j += 256)
        s += part[(size_t)j * stride + p];
#pragma unroll
    for (int off = 32; off > 0; off >>= 1) s += __shfl_down(s, off, 64);
    __shared__ float ls[4];
    if ((threadIdx.x & 63) == 0) ls[threadIdx.x >> 6] = s;
    __syncthreads();
    if (threadIdx.x == 0) stats[p] = ls[0] + ls[1] + ls[2] + ls[3];
}

// ---------- BN + ReLU + pool, fp16 in/out, 4 ch per thread ----------

__global__ __launch_bounds__(256) void bnpool2_kernel(
        const _Float16* __restrict__ Pt, const float* __restrict__ stats,
        const float* __restrict__ g, const float* __restrict__ bb,
        _Float16* __restrict__ out) {
    int t = blockIdx.x * 256 + threadIdx.x;
    if (t >= 1024 * 49 * 16) return;
    int c4 = (t & 15) * 4;
    int q2 = (t >> 4) % 49;
    int b  = t / (49 * 16);
    float sc[4], sh[4];
#pragma unroll
    for (int j = 0; j < 4; ++j) {
        int c = c4 + j;
        float mean = stats[2 * c] * (1.0f / 200704.0f);
        float var  = stats[2 * c + 1] * (1.0f / 200704.0f) - mean * mean;
        sc[j] = rsqrtf(var + BN_EPS) * g[c];
        sh[j] = bb[c] - mean * sc[j];
    }
    int py2 = q2 / 7, px2 = q2 - py2 * 7;
    int q = (py2 * 2) * 14 + px2 * 2;
    const _Float16* p = Pt + ((size_t)b * 196 + q) * 64 + c4;
    f16x4 r0 = *(const f16x4*)(p);
    f16x4 r1 = *(const f16x4*)(p + 64);
    f16x4 r2 = *(const f16x4*)(p + 14 * 64);
    f16x4 r3 = *(const f16x4*)(p + 15 * 64);
    f16x4 res;
#pragma unroll
    for (int j = 0; j < 4; ++j) {
        float v0 = fmaxf((float)r0[j] * sc[j] + sh[j], 0.f);
        float v1 = fmaxf((float)r1[j] * sc[j] + sh[j], 0.f);
        float v2 = fmaxf((float)r2[j] * sc[j] + sh[j], 0.f);
        float v3 = fmaxf((float)r3[j] * sc[j] + sh[j], 0.f);
        res[j] = (_Float16)fmaxf(fmaxf(v0, v1), fmaxf(v2, v3));
    }
    *(f16x4*)(out + (size_t)b * 3136 + q2 * 64 + c4) = res;
}

// ---------- fc1_w -> packed half2 wTh2[j2*64 + o] (k-pairs along flat j) ----------

__global__ __launch_bounds__(256) void transpose_kernel(
        const float* __restrict__ w, unsigned int* __restrict__ wTh2) {
    int t = blockIdx.x * 256 + threadIdx.x;
    if (t >= 64 * 1568) return;
    int o = t & 63;
    int j2 = t >> 6;
    int jc = (j2 * 2) & 63;
    int q2 = (j2 * 2) >> 6;
    wTh2[t] = (unsigned int)pkh(w[(size_t)o * 3136 + jc * 49 + q2],
                                w[(size_t)o * 3136 + (jc + 1) * 49 + q2]);
}

// ---------- fc1: fp16 x, packed-half2 weights, v_dot2_f32_f16 ----------

__global__ __launch_bounds__(256) void fc1_kernel(
        const _Float16* __restrict__ xin, const unsigned int* __restrict__ wTh2,
        const float* __restrict__ bias, float* __restrict__ z) {
    __shared__ unsigned int xsu[4 * 1568];
    __shared__ float red[4][4][64];
    int b0 = blockIdx.x * 4;
    const unsigned int* xg = (const unsigned int*)xin + (size_t)b0 * 1568;
    for (int j = threadIdx.x; j < 4 * 1568; j += 256) xsu[j] = xg[j];
    __syncthreads();
    int o = threadIdx.x & 63, q = threadIdx.x >> 6;
    float s0 = 0.f, s1 = 0.f, s2 = 0.f, s3 = 0.f;
    const unsigned int* wp = wTh2 + (size_t)q * 392 * 64 + o;
    int jb = q * 392;
    for (int i = 0; i < 392; ++i) {
        union { unsigned int u; fp16v2 h; } uw, u0, u1, u2, u3;
        uw.u = wp[i * 64];
        u0.u = xsu[jb + i];
        u1.u = xsu[1568 + jb + i];
        u2.u = xsu[2 * 1568 + jb + i];
        u3.u = xsu[3 * 1568 + jb + i];
        s0 = __builtin_amdgcn_fdot2(u0.h, uw.h, s0, false);
        s1 = __builtin_amdgcn_fdot2(u1.h, uw.h, s1, false);
        s2 = __builtin_amdgcn_fdot2(u2.h, uw.h, s2, false);
        s3 = __builtin_amdgcn_fdot2(u3.h, uw.h, s3, false);
    }
    red[0][q][o] = s0; red[1][q][o] = s1; red[2][q][o] = s2; red[3][q][o] = s3;
    __syncthreads();
    int bb = threadIdx.x >> 6;
    float tot = red[bb][0][o] + red[bb][1][o] + red[bb][2][o] + red[bb][3][o] + bias[o];
    z[((size_t)(b0 + bb)) * 64 + o] = tot;
}

// ---------- bn1d column stats over z [1024,64] ----------

__global__ __launch_bounds__(256) void colstats_kernel(
        const float* __restrict__ z, float* __restrict__ stats) {
    int c = blockIdx.x;
    float s = 0.f, s2 = 0.f;
    for (int b = threadIdx.x; b < 1024; b += 256) {
        float v = z[(size_t)b * 64 + c];
        s += v; s2 += v * v;
    }
#pragma unroll
    for (int off = 32; off > 0; off >>= 1) {
        s  += __shfl_down(s, off, 64);
        s2 += __shfl_down(s2, off, 64);
    }
    __shared__ float ls[8];
    int w = threadIdx.x >> 6;
    if ((threadIdx.x & 63) == 0) { ls[w * 2] = s; ls[w * 2 + 1] = s2; }
    __syncthreads();
    if (threadIdx.x == 0) {
        stats[2 * c]     = ls[0] + ls[2] + ls[4] + ls[6];
        stats[2 * c + 1] = ls[1] + ls[3] + ls[5] + ls[7];
    }
}

// ---------- final: bn1d + relu + fc2 -> out [1024,10] ----------

__global__ __launch_bounds__(256) void final_kernel(
        const float* __restrict__ z, const float* __restrict__ stats,
        const float* __restrict__ g, const float* __restrict__ bb,
        const float* __restrict__ w2, const float* __restrict__ b2,
        float* __restrict__ out) {
    int t = blockIdx.x * 256 + threadIdx.x;
    if (t >= 10240) return;
    int o = t % 10, b = t / 10;
    float acc = b2[o];
#pragma unroll 8
    for (int c = 0; c < 64; ++c) {
        float mean = stats[2 * c] * (1.0f / 1024.0f);
        float var  = stats[2 * c + 1] * (1.0f / 1024.0f) - mean * mean;
        float sc = rsqrtf(var + BN_EPS) * g[c];
        float a = fmaxf(z[(size_t)b * 64 + c] * sc + (bb[c] - mean * sc), 0.f);
        acc += a * w2[o * 64 + c];
    }
    out[t] = acc;
}

// ---------- launch ----------

extern "C" void kernel_launch(void* const* d_in, const int* in_sizes, int n_in,
                              void* d_out, int out_size, void* d_ws, size_t ws_size,
                              hipStream_t stream) {
    const float* x   = (const float*)d_in[0];
    const float* bw1 = (const float*)d_in[1];
    const float* sw1 = (const float*)d_in[2];
    const float* g1  = (const float*)d_in[3];
    const float* b1  = (const float*)d_in[4];
    const float* bw2 = (const float*)d_in[5];
    const float* sw2 = (const float*)d_in[6];
    const float* g2  = (const float*)d_in[7];
    const float* b2v = (const float*)d_in[8];
    const float* fw1 = (const float*)d_in[9];
    const float* fb1 = (const float*)d_in[10];
    const float* g3  = (const float*)d_in[11];
    const float* b3  = (const float*)d_in[12];
    const float* fw2 = (const float*)d_in[13];
    const float* fb2 = (const float*)d_in[14];
    float* out = (float*)d_out;

    char* ws = (char*)d_ws;
    // region A: part1 [16384][64] f32 (4.2 MB, dead after redstats1), then
    //   Pt fp16 [200704][64] (25.7 MB); part2 [4096][128] at +51,380,224
    float* part1     = (float*)(ws);
    _Float16* Pt     = (_Float16*)(ws);
    float* part2     = (float*)(ws + 51380224);
    _Float16* Wf     = (_Float16*)(ws + 100000000);
    _Float16* Wf1    = (_Float16*)(ws + 100131072);
    // region B: pooled fp16 [1024][225][32] (14.75 MB); later pooled2 fp16
    _Float16* pooled = (_Float16*)(ws + 125960192);
    float* z         = (float*)(ws + 155451392);          // [1024,64] f32
    unsigned int* wTh2 = (unsigned int*)(ws + 155713536); // [1568*64] packed
    float* stats1    = (float*)(ws + 156516352);
    float* stats2    = (float*)(ws + 156516608);
    float* stats3    = (float*)(ws + 156517120);

    transpose_kernel<<<392, 256, 0, stream>>>(fw1, wTh2);
    wconv16_kernel<<<160, 256, 0, stream>>>(bw2, sw2, Wf);
    wconv1h_kernel<<<8, 256, 0, stream>>>(bw1, sw1, Wf1);

    conv1_kernel<<<16384, 256, 0, stream>>>(x, Wf1, pooled, part1);
    redstats_kernel<<<64, 256, 0, stream>>>(part1, stats1, 16384, 64);

    conv2_kernel<<<4096, 256, 0, stream>>>(pooled, stats1, g1, b1,
                                           Wf, Pt, part2);
    redstats_kernel<<<128, 256, 0, stream>>>(part2, stats2, 4096, 128);

    _Float16* pooled2 = pooled;  // region B reuse
    bnpool2_kernel<<<(1024 * 49 * 16 + 255) / 256, 256, 0, stream>>>(
        Pt, stats2, g2, b2v, pooled2);

    fc1_kernel<<<256, 256, 0, stream>>>(pooled2, wTh2, fb1, z);
    colstats_kernel<<<64, 256, 0, stream>>>(z, stats3);
    final_kernel<<<(10240 + 255) / 256, 256, 0, stream>>>(z, stats3, g3, b3, fw2, fb2, out);
}

// Round 7
// 196.836 us; speedup vs baseline: 2.4676x; 1.1940x over previous
//
#include <hip/hip_runtime.h>
#include <math.h>

#define BN_EPS 1e-5f

typedef __attribute__((ext_vector_type(8))) _Float16 f16x8;
typedef __attribute__((ext_vector_type(4))) _Float16 f16x4;
typedef __attribute__((ext_vector_type(2))) __fp16 fp16v2;
typedef __attribute__((ext_vector_type(4))) float f32x4;

// ---------- helpers ----------

__device__ __forceinline__ float siluf(float v) {
    return v * __builtin_amdgcn_rcpf(1.0f + __expf(-v));
}

// 6*basis_i(x), i=0..3, cubic B-spline on knots g[j]=2j-7.
// 6*B(t) = max(0,2-|t|)^3 - 4*max(0,1-|t|)^3 with t = u-(i+2), u=(x+7)/2.
// The 1/6 is folded into the spline weights at prep time.
__device__ __forceinline__ void expand5(float v, float f[5]) {
    f[0] = siluf(v);
    float u = (v + 7.0f) * 0.5f;
#pragma unroll
    for (int i = 0; i < 4; ++i) {
        float a = fabsf(u - (float)(i + 2));
        float p = fmaxf(2.0f - a, 0.0f);
        float q = fmaxf(1.0f - a, 0.0f);
        f[i + 1] = p * p * p - 4.0f * (q * q * q);
    }
}

__device__ __forceinline__ int pkh(float a, float b) {
    union { fp16v2 h2; int i; } u;
    u.h2 = __builtin_amdgcn_cvt_pkrtz(a, b);
    return u.i;
}

// ---------- conv1 weights: Wf1[n][k], k = s*16 + f*3 + c (pad j=15 zero) ----------

__global__ __launch_bounds__(256) void wconv1h_kernel(
        const float* __restrict__ bw, const float* __restrict__ sw,
        _Float16* __restrict__ Wf1) {
    int t = blockIdx.x * 256 + threadIdx.x;
    if (t >= 32 * 64) return;
    int n = t >> 6;
    int k = t & 63;
    int s = k >> 4, j = k & 15;
    float val = 0.f;
    if (j < 15) {
        int f = j / 3, c = j - f * 3;
        int i = c * 4 + s;
        val = (f == 0) ? bw[n * 12 + i]
                       : sw[(n * 12 + i) * 4 + f - 1] * (1.0f / 6.0f);
    }
    Wf1[t] = (_Float16)val;
}

// ---------- conv1: per-IMAGE block, unique-pixel expand + MFMA + pool + stats ----
// 1024 blocks. Phase 1: all 32x32x3 unique pixels expanded once (12/thread)
// into Eu[pos][16 halves] (32B rows), XOR-swizzled: byte ^= (pos&12)<<2 ->
// conflict-free b128 reads (8-row bank bases {0,8,16,24,4,12,20,28}).
// Row 1024 = zero row for invalid windows (wy==31 or wx==31).
// Phase 2: wave wv sweeps column strip tx=wv over 16 row-tiles; ds_read for
// tile i+1 issued under tile i's epilogue; stats accumulate in regs, reduced
// once; pool in-register (4 windows/lane + shfl 32).

__global__ __launch_bounds__(256, 4) void conv1_kernel(
        const float* __restrict__ x, const _Float16* __restrict__ Wf1,
        _Float16* __restrict__ pooled, float* __restrict__ part) {
    __shared__ _Float16 Eu[1025 * 16];
    __shared__ float Rs[4][64];
    char* EuB = (char*)Eu;

    int t = threadIdx.x;
    int lane = t & 63, wv = t >> 6;
    int quad = lane >> 4, l15 = lane & 15;
    int b = blockIdx.x;

    const _Float16* wb0 = Wf1 + (size_t)l15 * 64 + quad * 8;
    f16x8 bf00 = *(const f16x8*)(wb0);
    f16x8 bf01 = *(const f16x8*)(wb0 + 32);
    f16x8 bf10 = *(const f16x8*)(wb0 + 16 * 64);
    f16x8 bf11 = *(const f16x8*)(wb0 + 16 * 64 + 32);

    // ---- phase 1 ----
    float xv[12];
    const float* xb = x + (size_t)b * 3072;
#pragma unroll
    for (int k = 0; k < 12; ++k) xv[k] = xb[t + k * 256];
#pragma unroll
    for (int k = 0; k < 12; ++k) {
        int idx = t + k * 256;
        int c = idx >> 10;
        int pos = idx & 1023;
        float f[5];
        expand5(xv[k], f);
        int rb = pos * 32;
        int key = (pos & 12) << 2;
        *(_Float16*)(EuB + ((rb + c * 2) ^ key))        = (_Float16)f[0];
        *(_Float16*)(EuB + ((rb + (3 + c) * 2) ^ key))  = (_Float16)f[1];
        *(_Float16*)(EuB + ((rb + (6 + c) * 2) ^ key))  = (_Float16)f[2];
        *(_Float16*)(EuB + ((rb + (9 + c) * 2) ^ key))  = (_Float16)f[3];
        *(_Float16*)(EuB + ((rb + (12 + c) * 2) ^ key)) = (_Float16)f[4];
    }
    if (t < 8) *(int*)(EuB + 32768 + t * 4) = 0;  // zero row (pos 1024)
    __syncthreads();

    // ---- phase 2 ----
    int dxq = quad >> 1, hb = (quad & 1) * 16;
    int wxv = 8 * wv + (l15 & 7);            // tx = wv (column strip)
    int colb = wxv + dxq;
    int pbase = (colb * 32 + hb) ^ ((colb & 12) << 2);
    bool vx = wxv < 31;
    int pzero = 32768 + hb;
    int wy0 = l15 >> 3;

    float ss0 = 0.f, sq0 = 0.f, ss1 = 0.f, sq1 = 0.f;

    int wy = wy0;                            // i = 0: wy < 31 always
    int p0 = vx ? wy * 1024 + pbase : pzero;
    f16x8 a0 = *(const f16x8*)(EuB + p0);
    f16x8 a1 = *(const f16x8*)(EuB + p0 + (vx ? 1024 : 0));

#pragma unroll 1
    for (int i = 0; i < 16; ++i) {
        f32x4 acc0 = (f32x4){0.f, 0.f, 0.f, 0.f};
        f32x4 acc1 = (f32x4){0.f, 0.f, 0.f, 0.f};
        acc0 = __builtin_amdgcn_mfma_f32_16x16x32_f16(a0, bf00, acc0, 0, 0, 0);
        acc1 = __builtin_amdgcn_mfma_f32_16x16x32_f16(a0, bf10, acc1, 0, 0, 0);
        acc0 = __builtin_amdgcn_mfma_f32_16x16x32_f16(a1, bf01, acc0, 0, 0, 0);
        acc1 = __builtin_amdgcn_mfma_f32_16x16x32_f16(a1, bf11, acc1, 0, 0, 0);
        if (i < 15) {
            int wyn = 2 * (i + 1) + wy0;
            bool vn = vx && (wyn < 31);
            int pn = vn ? wyn * 1024 + pbase : pzero;
            a0 = *(const f16x8*)(EuB + pn);
            a1 = *(const f16x8*)(EuB + pn + (vn ? 1024 : 0));
        }
        // pool (C rows quad*4+reg = windows; wy = 2i + quad>>1)
        float h00 = fmaxf(acc0[0], acc0[1]);
        float h01 = fmaxf(acc0[2], acc0[3]);
        float h10 = fmaxf(acc1[0], acc1[1]);
        float h11 = fmaxf(acc1[2], acc1[3]);
        float g00 = fmaxf(h00, __shfl_down(h00, 32, 64));
        float g01 = fmaxf(h01, __shfl_down(h01, 32, 64));
        float g10 = fmaxf(h10, __shfl_down(h10, 32, 64));
        float g11 = fmaxf(h11, __shfl_down(h11, 32, 64));
        if (lane < 32 && i < 15) {
            int pn0 = 4 * wv + (quad & 1) * 2;
            size_t base = ((size_t)b * 225 + i * 15) * 32;
            if (pn0 < 15) {
                pooled[base + pn0 * 32 + l15]      = (_Float16)g00;
                pooled[base + pn0 * 32 + 16 + l15] = (_Float16)g10;
            }
            if (pn0 < 14) {
                pooled[base + (pn0 + 1) * 32 + l15]      = (_Float16)g01;
                pooled[base + (pn0 + 1) * 32 + 16 + l15] = (_Float16)g11;
            }
        }
        ss0 += acc0[0] + acc0[1] + acc0[2] + acc0[3];
        sq0 += acc0[0] * acc0[0] + acc0[1] * acc0[1]
             + acc0[2] * acc0[2] + acc0[3] * acc0[3];
        ss1 += acc1[0] + acc1[1] + acc1[2] + acc1[3];
        sq1 += acc1[0] * acc1[0] + acc1[1] * acc1[1]
             + acc1[2] * acc1[2] + acc1[3] * acc1[3];
    }

    ss0 += __shfl_down(ss0, 32, 64); ss0 += __shfl_down(ss0, 16, 64);
    sq0 += __shfl_down(sq0, 32, 64); sq0 += __shfl_down(sq0, 16, 64);
    ss1 += __shfl_down(ss1, 32, 64); ss1 += __shfl_down(ss1, 16, 64);
    sq1 += __shfl_down(sq1, 32, 64); sq1 += __shfl_down(sq1, 16, 64);
    if (lane < 16) {
        Rs[wv][2 * l15]          = ss0;
        Rs[wv][2 * l15 + 1]      = sq0;
        Rs[wv][32 + 2 * l15]     = ss1;
        Rs[wv][32 + 2 * l15 + 1] = sq1;
    }
    __syncthreads();
    if (t < 64)
        part[(size_t)b * 64 + t] = Rs[0][t] + Rs[1][t] + Rs[2][t] + Rs[3][t];
}

// ---------- conv2 weights fp16, k = s*160 + f*32 + c (spline scaled 1/6) ----------

__global__ __launch_bounds__(256) void wconv16_kernel(
        const float* __restrict__ bw, const float* __restrict__ sw,
        _Float16* __restrict__ Wf) {
    int t = blockIdx.x * 256 + threadIdx.x;
    if (t >= 64 * 640) return;
    int n = t / 640;
    int k = t - n * 640;
    int s = k / 160;
    int r = k - s * 160;
    int f = r >> 5;
    int c = r & 31;
    float val = (f == 0) ? bw[n * 128 + c * 4 + s]
                         : sw[n * 512 + c * 16 + s * 4 + (f - 1)] * (1.0f / 6.0f);
    Wf[t] = (_Float16)val;
}

// ---------- conv2: unique-pixel expansion + barrier-free MFMA ----------
// Phase-1 thread map = (c2, xx, yh) with yr in the inner loop: wave lanes span
// 4 xx values (bank bases {0,20,8,28}) instead of 4 yr values (all base-equal)
// -> write conflicts 4-way -> ~2-way.

#define EU_LDW 168

__device__ __forceinline__ void c2_loadb(const _Float16* __restrict__ Wb,
                                         int g, f16x8 bf[5]) {
#pragma unroll
    for (int ks = 0; ks < 5; ++ks)
        bf[ks] = *(const f16x8*)(Wb + g * 160 + ks * 32);
}

__device__ __forceinline__ void c2_mfma(const _Float16* Eu,
                                        const int abase[4][4], int g,
                                        int quad, const f16x8 bf[5],
                                        f32x4 acc[4]) {
#pragma unroll
    for (int ks = 0; ks < 5; ++ks) {
        int jo = ks * 32 + quad * 8;
#pragma unroll
        for (int mt = 0; mt < 4; ++mt) {
            f16x8 a = *(const f16x8*)&Eu[abase[mt][g] + jo];
            acc[mt] = __builtin_amdgcn_mfma_f32_16x16x32_f16(a, bf[ks], acc[mt], 0, 0, 0);
        }
    }
}

__global__ __launch_bounds__(256, 7) void conv2_kernel(
        const _Float16* __restrict__ pooled, const float* __restrict__ stats1,
        const float* __restrict__ g1v, const float* __restrict__ b1v,
        const _Float16* __restrict__ Wf, _Float16* __restrict__ Pt,
        float* __restrict__ part) {
    __shared__ _Float16 Eu[65 * EU_LDW];

    int t = threadIdx.x;
    int lane = t & 63, wv = t >> 6;
    int quad = lane >> 4, l15 = lane & 15;

    int blk = blockIdx.x;
    int b = blk >> 2;
    int py0 = ((blk >> 1) & 1) * 7;
    int px0 = (blk & 1) * 7;

    const _Float16* Wb = Wf + (size_t)(wv * 16 + l15) * 640 + quad * 8;
    f16x8 bfA[5], bfB[5];
    c2_loadb(Wb, 0, bfA);

    // ---- phase 1: 8x8 pixels x 32 ch; thread = (c-pair, xx, y-half) ----
    {
        int c2 = t & 15, c0 = c2 * 2;
        int xx = (t >> 4) & 7;
        int yh = t >> 7;
        const float invN1 = 1.0f / (1024.0f * 961.0f);
        float m0 = stats1[2 * c0] * invN1;
        float v0 = stats1[2 * c0 + 1] * invN1 - m0 * m0;
        float sc0 = rsqrtf(v0 + BN_EPS) * g1v[c0];
        float sh0 = b1v[c0] - m0 * sc0;
        float m1 = stats1[2 * c0 + 2] * invN1;
        float v1 = stats1[2 * c0 + 3] * invN1 - m1 * m1;
        float sc1 = rsqrtf(v1 + BN_EPS) * g1v[c0 + 1];
        float sh1 = b1v[c0 + 1] - m1 * sc1;
        const _Float16* pbase0 =
            pooled + ((size_t)b * 225 + py0 * 15 + px0) * 32 + c0;
#pragma unroll
        for (int yi = 0; yi < 4; ++yi) {
            int yr = yh * 4 + yi;
            fp16v2 v2 = *(const fp16v2*)(pbase0 + yr * 480 + xx * 32);
            float va = fmaxf((float)v2.x * sc0 + sh0, 0.f);
            float vb = fmaxf((float)v2.y * sc1 + sh1, 0.f);
            float fa[5], fb5[5];
            expand5(va, fa);
            expand5(vb, fb5);
            int* eb = (int*)&Eu[(yr * 8 + xx) * EU_LDW + c0];
            eb[0]  = pkh(fa[0], fb5[0]);
            eb[16] = pkh(fa[1], fb5[1]);
            eb[32] = pkh(fa[2], fb5[2]);
            eb[48] = pkh(fa[3], fb5[3]);
            eb[64] = pkh(fa[4], fb5[4]);
        }
    }
    if (t < 84) *(int*)((char*)&Eu[64 * EU_LDW] + t * 4) = 0;

    int abase[4][4];
#pragma unroll
    for (int mt = 0; mt < 4; ++mt) {
        int m = mt * 16 + l15;
        if (m < 49) {
            int pr = m / 7, pc = m - pr * 7;
#pragma unroll
            for (int s = 0; s < 4; ++s)
                abase[mt][s] = ((pr + (s >> 1)) * 8 + pc + (s & 1)) * EU_LDW;
        } else {
#pragma unroll
            for (int s = 0; s < 4; ++s) abase[mt][s] = 64 * EU_LDW;
        }
    }
    __syncthreads();

    f32x4 acc[4];
#pragma unroll
    for (int mt = 0; mt < 4; ++mt) acc[mt] = (f32x4){0.f, 0.f, 0.f, 0.f};

    c2_loadb(Wb, 1, bfB);
    c2_mfma(Eu, abase, 0, quad, bfA, acc);
    c2_loadb(Wb, 2, bfA);
    c2_mfma(Eu, abase, 1, quad, bfB, acc);
    c2_loadb(Wb, 3, bfB);
    c2_mfma(Eu, abase, 2, quad, bfA, acc);
    c2_mfma(Eu, abase, 3, quad, bfB, acc);

    // ---- store fp16 Pt ----
    int o = wv * 16 + l15;
#pragma unroll
    for (int mt = 0; mt < 4; ++mt) {
#pragma unroll
        for (int reg = 0; reg < 4; ++reg) {
            int m = mt * 16 + quad * 4 + reg;
            if (m < 49) {
                int pr = m / 7, pc = m - pr * 7;
                int patch = (b * 14 + py0 + pr) * 14 + px0 + pc;
                Pt[(size_t)patch * 64 + o] = (_Float16)acc[mt][reg];
            }
        }
    }
    float s = 0.f, s2 = 0.f;
#pragma unroll
    for (int mt = 0; mt < 4; ++mt)
#pragma unroll
        for (int reg = 0; reg < 4; ++reg) {
            float a = acc[mt][reg];
            s += a;
            s2 += a * a;
        }
    s  += __shfl_down(s, 16, 64);  s  += __shfl_down(s, 32, 64);
    s2 += __shfl_down(s2, 16, 64); s2 += __shfl_down(s2, 32, 64);
    if (lane < 16) {
        part[(size_t)blk * 128 + 2 * o]     = s;
        part[(size_t)blk * 128 + 2 * o + 1] = s2;
    }
}

// ---------- reduce slot-major partials ----------

__global__ __launch_bounds__(256) void redstats_kernel(
        const float* __restrict__ part, float* __restrict__ stats,
        int nblk, int stride) {
    int p = blockIdx.x;
    float s = 0.f;
    for (int j = threadIdx.x; j < nblk; j += 256)
        s += part[(size_t)j * stride + p];
#pragma unroll
    for (int off = 32; off > 0; off >>= 1) s += __shfl_down(s, off, 64);
    __shared__ float ls[4];
    if ((threadIdx.x & 63) == 0) ls[threadIdx.x >> 6] = s;
    __syncthreads();
    if (threadIdx.x == 0) stats[p] = ls[0] + ls[1] + ls[2] + ls[3];
}

// ---------- BN + ReLU + pool, fp16 in/out, 4 ch per thread ----------

__global__ __launch_bounds__(256) void bnpool2_kernel(
        const _Float16* __restrict__ Pt, const float* __restrict__ stats,
        const float* __restrict__ g, const float* __restrict__ bb,
        _Float16* __restrict__ out) {
    int t = blockIdx.x * 256 + threadIdx.x;
    if (t >= 1024 * 49 * 16) return;
    int c4 = (t & 15) * 4;
    int q2 = (t >> 4) % 49;
    int b  = t / (49 * 16);
    float sc[4], sh[4];
#pragma unroll
    for (int j = 0; j < 4; ++j) {
        int c = c4 + j;
        float mean = stats[2 * c] * (1.0f / 200704.0f);
        float var  = stats[2 * c + 1] * (1.0f / 200704.0f) - mean * mean;
        sc[j] = rsqrtf(var + BN_EPS) * g[c];
        sh[j] = bb[c] - mean * sc[j];
    }
    int py2 = q2 / 7, px2 = q2 - py2 * 7;
    int q = (py2 * 2) * 14 + px2 * 2;
    const _Float16* p = Pt + ((size_t)b * 196 + q) * 64 + c4;
    f16x4 r0 = *(const f16x4*)(p);
    f16x4 r1 = *(const f16x4*)(p + 64);
    f16x4 r2 = *(const f16x4*)(p + 14 * 64);
    f16x4 r3 = *(const f16x4*)(p + 15 * 64);
    f16x4 res;
#pragma unroll
    for (int j = 0; j < 4; ++j) {
        float v0 = fmaxf((float)r0[j] * sc[j] + sh[j], 0.f);
        float v1 = fmaxf((float)r1[j] * sc[j] + sh[j], 0.f);
        float v2 = fmaxf((float)r2[j] * sc[j] + sh[j], 0.f);
        float v3 = fmaxf((float)r3[j] * sc[j] + sh[j], 0.f);
        res[j] = (_Float16)fmaxf(fmaxf(v0, v1), fmaxf(v2, v3));
    }
    *(f16x4*)(out + (size_t)b * 3136 + q2 * 64 + c4) = res;
}

// ---------- fc1_w -> packed half2 wTh2[j2*64 + o] ----------

__global__ __launch_bounds__(256) void transpose_kernel(
        const float* __restrict__ w, unsigned int* __restrict__ wTh2) {
    int t = blockIdx.x * 256 + threadIdx.x;
    if (t >= 64 * 1568) return;
    int o = t & 63;
    int j2 = t >> 6;
    int jc = (j2 * 2) & 63;
    int q2 = (j2 * 2) >> 6;
    wTh2[t] = (unsigned int)pkh(w[(size_t)o * 3136 + jc * 49 + q2],
                                w[(size_t)o * 3136 + (jc + 1) * 49 + q2]);
}

// ---------- fc1: fp16 x, packed-half2 weights, v_dot2_f32_f16 ----------

__global__ __launch_bounds__(256) void fc1_kernel(
        const _Float16* __restrict__ xin, const unsigned int* __restrict__ wTh2,
        const float* __restrict__ bias, float* __restrict__ z) {
    __shared__ unsigned int xsu[4 * 1568];
    __shared__ float red[4][4][64];
    int b0 = blockIdx.x * 4;
    const unsigned int* xg = (const unsigned int*)xin + (size_t)b0 * 1568;
    for (int j = threadIdx.x; j < 4 * 1568; j += 256) xsu[j] = xg[j];
    __syncthreads();
    int o = threadIdx.x & 63, q = threadIdx.x >> 6;
    float s0 = 0.f, s1 = 0.f, s2 = 0.f, s3 = 0.f;
    const unsigned int* wp = wTh2 + (size_t)q * 392 * 64 + o;
    int jb = q * 392;
    for (int i = 0; i < 392; ++i) {
        union { unsigned int u; fp16v2 h; } uw, u0, u1, u2, u3;
        uw.u = wp[i * 64];
        u0.u = xsu[jb + i];
        u1.u = xsu[1568 + jb + i];
        u2.u = xsu[2 * 1568 + jb + i];
        u3.u = xsu[3 * 1568 + jb + i];
        s0 = __builtin_amdgcn_fdot2(u0.h, uw.h, s0, false);
        s1 = __builtin_amdgcn_fdot2(u1.h, uw.h, s1, false);
        s2 = __builtin_amdgcn_fdot2(u2.h, uw.h, s2, false);
        s3 = __builtin_amdgcn_fdot2(u3.h, uw.h, s3, false);
    }
    red[0][q][o] = s0; red[1][q][o] = s1; red[2][q][o] = s2; red[3][q][o] = s3;
    __syncthreads();
    int bb = threadIdx.x >> 6;
    float tot = red[bb][0][o] + red[bb][1][o] + red[bb][2][o] + red[bb][3][o] + bias[o];
    z[((size_t)(b0 + bb)) * 64 + o] = tot;
}

// ---------- bn1d column stats -> precomputed sc/sh ----------

__global__ __launch_bounds__(256) void colstats_kernel(
        const float* __restrict__ z, const float* __restrict__ g,
        const float* __restrict__ bb, float* __restrict__ scsh) {
    int c = blockIdx.x;
    float s = 0.f, s2 = 0.f;
    for (int b = threadIdx.x; b < 1024; b += 256) {
        float v = z[(size_t)b * 64 + c];
        s += v; s2 += v * v;
    }
#pragma unroll
    for (int off = 32; off > 0; off >>= 1) {
        s  += __shfl_down(s, off, 64);
        s2 += __shfl_down(s2, off, 64);
    }
    __shared__ float ls[8];
    int w = threadIdx.x >> 6;
    if ((threadIdx.x & 63) == 0) { ls[w * 2] = s; ls[w * 2 + 1] = s2; }
    __syncthreads();
    if (threadIdx.x == 0) {
        float st = ls[0] + ls[2] + ls[4] + ls[6];
        float st2 = ls[1] + ls[3] + ls[5] + ls[7];
        float mean = st * (1.0f / 1024.0f);
        float var  = st2 * (1.0f / 1024.0f) - mean * mean;
        float sc = rsqrtf(var + BN_EPS) * g[c];
        scsh[2 * c]     = sc;
        scsh[2 * c + 1] = bb[c] - mean * sc;
    }
}

// ---------- final: bn1d + relu + fc2 -> out [1024,10] ----------

__global__ __launch_bounds__(256) void final_kernel(
        const float* __restrict__ z, const float* __restrict__ scsh,
        const float* __restrict__ w2, const float* __restrict__ b2,
        float* __restrict__ out) {
    int t = blockIdx.x * 256 + threadIdx.x;
    if (t >= 10240) return;
    int o = t % 10, b = t / 10;
    float acc = b2[o];
#pragma unroll 8
    for (int c = 0; c < 64; ++c) {
        float a = fmaxf(z[(size_t)b * 64 + c] * scsh[2 * c] + scsh[2 * c + 1], 0.f);
        acc += a * w2[o * 64 + c];
    }
    out[t] = acc;
}

// ---------- launch ----------

extern "C" void kernel_launch(void* const* d_in, const int* in_sizes, int n_in,
                              void* d_out, int out_size, void* d_ws, size_t ws_size,
                              hipStream_t stream) {
    const float* x   = (const float*)d_in[0];
    const float* bw1 = (const float*)d_in[1];
    const float* sw1 = (const float*)d_in[2];
    const float* g1  = (const float*)d_in[3];
    const float* b1  = (const float*)d_in[4];
    const float* bw2 = (const float*)d_in[5];
    const float* sw2 = (const float*)d_in[6];
    const float* g2  = (const float*)d_in[7];
    const float* b2v = (const float*)d_in[8];
    const float* fw1 = (const float*)d_in[9];
    const float* fb1 = (const float*)d_in[10];
    const float* g3  = (const float*)d_in[11];
    const float* b3  = (const float*)d_in[12];
    const float* fw2 = (const float*)d_in[13];
    const float* fb2 = (const float*)d_in[14];
    float* out = (float*)d_out;

    char* ws = (char*)d_ws;
    // region A: part1 [1024][64] f32 (256 KB, dead after redstats1), then
    //   Pt fp16 [200704][64] (25.7 MB); part2 [4096][128] at +51,380,224
    float* part1     = (float*)(ws);
    _Float16* Pt     = (_Float16*)(ws);
    float* part2     = (float*)(ws + 51380224);
    _Float16* Wf     = (_Float16*)(ws + 100000000);
    _Float16* Wf1    = (_Float16*)(ws + 100131072);
    // region B: pooled fp16 [1024][225][32] (14.75 MB); later pooled2 fp16
    _Float16* pooled = (_Float16*)(ws + 125960192);
    float* z         = (float*)(ws + 155451392);          // [1024,64] f32
    unsigned int* wTh2 = (unsigned int*)(ws + 155713536); // [1568*64] packed
    float* stats1    = (float*)(ws + 156516352);
    float* stats2    = (float*)(ws + 156516608);
    float* stats3    = (float*)(ws + 156517120);

    transpose_kernel<<<392, 256, 0, stream>>>(fw1, wTh2);
    wconv16_kernel<<<160, 256, 0, stream>>>(bw2, sw2, Wf);
    wconv1h_kernel<<<8, 256, 0, stream>>>(bw1, sw1, Wf1);

    conv1_kernel<<<1024, 256, 0, stream>>>(x, Wf1, pooled, part1);
    redstats_kernel<<<64, 256, 0, stream>>>(part1, stats1, 1024, 64);

    conv2_kernel<<<4096, 256, 0, stream>>>(pooled, stats1, g1, b1,
                                           Wf, Pt, part2);
    redstats_kernel<<<128, 256, 0, stream>>>(part2, stats2, 4096, 128);

    _Float16* pooled2 = pooled;  // region B reuse
    bnpool2_kernel<<<(1024 * 49 * 16 + 255) / 256, 256, 0, stream>>>(
        Pt, stats2, g2, b2v, pooled2);

    fc1_kernel<<<256, 256, 0, stream>>>(pooled2, wTh2, fb1, z);
    colstats_kernel<<<64, 256, 0, stream>>>(z, g3, b3, stats3);
    final_kernel<<<(10240 + 255) / 256, 256, 0, stream>>>(z, stats3, fw2, fb2, out);
}